// Round 1
// baseline (5588.648 us; speedup 1.0000x reference)
//
#include <hip/hip_runtime.h>
#include <math.h>

// ---------------- sizes (runtime-derived, constants here for reference) ----
// N=100000, E=1600000, G=64, H=4, C=64, NODE_F=32, DRONE_F=16, OUT=32, L=2

#define NEG_SLOPE 0.2f
#define LN_EPS 1e-5f

// ---------------------------------------------------------------------------
// dr[g][c] = drone_feat[g] @ drone_W[c] + drone_b[c]
__global__ void k_dr(const float* __restrict__ drone_feat,
                     const float* __restrict__ drone_W,
                     const float* __restrict__ drone_b,
                     float* __restrict__ dr, int G) {
    int i = blockIdx.x * blockDim.x + threadIdx.x;  // g*64 + c
    if (i >= G * 64) return;
    int g = i >> 6, c = i & 63;
    float acc = drone_b[c];
    const float* df = drone_feat + g * 16;
    const float* w  = drone_W + c * 16;
#pragma unroll
    for (int j = 0; j < 16; ++j) acc += df[j] * w[j];
    dr[i] = acc;
}

// h[n][c] = x[n] @ node_W[c] + node_b[c] + dr[batch[n]][c]
__global__ void k_h0(const float* __restrict__ x,
                     const int* __restrict__ batch,
                     const float* __restrict__ node_W,
                     const float* __restrict__ node_b,
                     const float* __restrict__ dr,
                     float* __restrict__ h, int N) {
    int i = blockIdx.x * blockDim.x + threadIdx.x;  // n*64 + c
    if (i >= N * 64) return;
    int n = i >> 6, c = i & 63;
    float acc = node_b[c] + dr[batch[n] * 64 + c];
    const float* xr = x + n * 32;
    const float* w  = node_W + c * 32;
#pragma unroll
    for (int k = 0; k < 32; ++k) acc += xr[k] * w[k];
    h[i] = acc;
}

// deg[n] = 1 (self loop)
__global__ void k_deg_init(int* __restrict__ deg, int N) {
    int i = blockIdx.x * blockDim.x + threadIdx.x;
    if (i < N) deg[i] = 1;
}

// histogram of dst
__global__ void k_count(const int* __restrict__ edge_index, int* __restrict__ deg, int E) {
    int i = blockIdx.x * blockDim.x + threadIdx.x;
    if (i < E) atomicAdd(deg + edge_index[E + i], 1);
}

// single-block exclusive scan of deg -> rowptr (and cursor copy)
__global__ void k_scan(const int* __restrict__ deg, int* __restrict__ rowptr,
                       int* __restrict__ cursor, int N) {
    __shared__ int part[1024];
    int t = threadIdx.x;
    int chunk = (N + 1023) >> 10;
    int start = t * chunk;
    int end = start + chunk; if (end > N) end = N; if (start > N) start = N;
    int sum = 0;
    for (int i = start; i < end; ++i) sum += deg[i];
    part[t] = sum;
    __syncthreads();
    for (int off = 1; off < 1024; off <<= 1) {
        int v = (t >= off) ? part[t - off] : 0;
        __syncthreads();
        part[t] += v;
        __syncthreads();
    }
    int base = part[t] - sum;  // exclusive prefix
    for (int i = start; i < end; ++i) {
        rowptr[i] = base;
        cursor[i] = base;
        base += deg[i];
    }
    if (t == 1023) rowptr[N] = part[1023];
}

// scatter src ids into dst-sorted CSR (self loops appended)
__global__ void k_scatter(const int* __restrict__ edge_index, int* __restrict__ cursor,
                          int* __restrict__ csr, int E, int N) {
    int i = blockIdx.x * blockDim.x + threadIdx.x;
    if (i >= E + N) return;
    int s, d;
    if (i < E) { s = edge_index[i]; d = edge_index[E + i]; }
    else       { s = i - E; d = s; }
    int pos = atomicAdd(cursor + d, 1);
    csr[pos] = s;
}

// xh[n][256] = h[n] @ convW.T ; as/ad[n][h] = <xh[n,h,:], att_src/dst[h,:]>
// 8 nodes per block of 256 threads; thread t owns output channel t for all 8.
__global__ void k_xh(const float* __restrict__ h, const float* __restrict__ convW,
                     const float* __restrict__ att_src, const float* __restrict__ att_dst,
                     float* __restrict__ xh, float* __restrict__ as_, float* __restrict__ ad_,
                     int N) {
    __shared__ float hs[8][64];
    int t = threadIdx.x;
    int n0 = blockIdx.x * 8;
    for (int i = t; i < 8 * 64; i += 256) {
        int n = n0 + (i >> 6);
        hs[i >> 6][i & 63] = (n < N) ? h[n * 64 + (i & 63)] : 0.f;
    }
    __syncthreads();
    const float4* w4 = (const float4*)(convW + t * 64);
    float acc[8];
#pragma unroll
    for (int j = 0; j < 8; ++j) acc[j] = 0.f;
    for (int k4 = 0; k4 < 16; ++k4) {
        float4 wv = w4[k4];
        int k = k4 * 4;
#pragma unroll
        for (int j = 0; j < 8; ++j) {
            acc[j] += hs[j][k] * wv.x + hs[j][k + 1] * wv.y +
                      hs[j][k + 2] * wv.z + hs[j][k + 3] * wv.w;
        }
    }
    float asv = att_src[t], adv = att_dst[t];
    int head = t >> 6, lane = t & 63;
#pragma unroll
    for (int j = 0; j < 8; ++j) {
        int n = n0 + j;
        if (n < N) xh[n * 256 + t] = acc[j];
        float vs = acc[j] * asv;
        float vd = acc[j] * adv;
#pragma unroll
        for (int off = 32; off >= 1; off >>= 1) {
            vs += __shfl_xor(vs, off, 64);
            vd += __shfl_xor(vd, off, 64);
        }
        if (lane == 0 && n < N) {
            as_[n * 4 + head] = vs;
            ad_[n * 4 + head] = vd;
        }
    }
}

// One wave per dst node: online softmax over incoming edges, fused
// head-mean + bias + LayerNorm + ReLU + residual (h += ...).
__global__ void k_gat(const float* __restrict__ xh, const float* __restrict__ as_,
                      const float* __restrict__ ad_, const int* __restrict__ rowptr,
                      const int* __restrict__ csr, const float* __restrict__ convb,
                      const float* __restrict__ ln_g, const float* __restrict__ ln_b,
                      float* __restrict__ h, int N) {
    int wid = threadIdx.x >> 6, lane = threadIdx.x & 63;
    int n = blockIdx.x * 4 + wid;
    if (n >= N) return;
    int r0 = rowptr[n], r1 = rowptr[n + 1];
    float4 adv = *(const float4*)(ad_ + (size_t)n * 4);
    float m0 = -INFINITY, m1 = -INFINITY, m2 = -INFINITY, m3 = -INFINITY;
    float s0 = 0.f, s1 = 0.f, s2 = 0.f, s3 = 0.f;
    float a0 = 0.f, a1 = 0.f, a2 = 0.f, a3 = 0.f;
    for (int i = r0; i < r1; ++i) {
        int src = csr[i];
        float4 asv = *(const float4*)(as_ + (size_t)src * 4);
        const float* xr = xh + (size_t)src * 256 + lane;
        float e, nm, sc, w;
        e = asv.x + adv.x; e = e > 0.f ? e : NEG_SLOPE * e;
        nm = fmaxf(m0, e); sc = __expf(m0 - nm); w = __expf(e - nm);
        s0 = s0 * sc + w; a0 = a0 * sc + w * xr[0];   m0 = nm;
        e = asv.y + adv.y; e = e > 0.f ? e : NEG_SLOPE * e;
        nm = fmaxf(m1, e); sc = __expf(m1 - nm); w = __expf(e - nm);
        s1 = s1 * sc + w; a1 = a1 * sc + w * xr[64];  m1 = nm;
        e = asv.z + adv.z; e = e > 0.f ? e : NEG_SLOPE * e;
        nm = fmaxf(m2, e); sc = __expf(m2 - nm); w = __expf(e - nm);
        s2 = s2 * sc + w; a2 = a2 * sc + w * xr[128]; m2 = nm;
        e = asv.w + adv.w; e = e > 0.f ? e : NEG_SLOPE * e;
        nm = fmaxf(m3, e); sc = __expf(m3 - nm); w = __expf(e - nm);
        s3 = s3 * sc + w; a3 = a3 * sc + w * xr[192]; m3 = nm;
    }
    float o = a0 / (s0 + 1e-16f) + a1 / (s1 + 1e-16f) +
              a2 / (s2 + 1e-16f) + a3 / (s3 + 1e-16f);
    o = 0.25f * o + convb[lane];
    // LayerNorm across the wave (64 channels)
    float mu = o;
#pragma unroll
    for (int off = 32; off >= 1; off >>= 1) mu += __shfl_xor(mu, off, 64);
    mu *= (1.f / 64.f);
    float d = o - mu;
    float v = d * d;
#pragma unroll
    for (int off = 32; off >= 1; off >>= 1) v += __shfl_xor(v, off, 64);
    v *= (1.f / 64.f);
    float y = d * rsqrtf(v + LN_EPS) * ln_g[lane] + ln_b[lane];
    y = fmaxf(y, 0.f);
    h[(size_t)n * 64 + lane] += y;
}

// out[n][o] = h[n] @ out_W[o] + out_b[o]
__global__ void k_out(const float* __restrict__ h, const float* __restrict__ out_W,
                      const float* __restrict__ out_b, float* __restrict__ out, int N) {
    __shared__ float hs[8][64];
    int t = threadIdx.x;
    int n0 = blockIdx.x * 8;
    for (int i = t; i < 512; i += 256) {
        int n = n0 + (i >> 6);
        hs[i >> 6][i & 63] = (n < N) ? h[n * 64 + (i & 63)] : 0.f;
    }
    __syncthreads();
    int j = t >> 5, o = t & 31;
    int n = n0 + j;
    if (n >= N) return;
    float acc = out_b[o];
    const float* w = out_W + o * 64;
#pragma unroll
    for (int k = 0; k < 64; ++k) acc += hs[j][k] * w[k];
    out[n * 32 + o] = acc;
}

static inline unsigned cdiv(long long a, long long b) { return (unsigned)((a + b - 1) / b); }

extern "C" void kernel_launch(void* const* d_in, const int* in_sizes, int n_in,
                              void* d_out, int out_size, void* d_ws, size_t ws_size,
                              hipStream_t stream) {
    const float* x          = (const float*)d_in[0];
    const float* drone_feat = (const float*)d_in[1];
    const int*   edge_index = (const int*)d_in[2];
    const int*   batch      = (const int*)d_in[3];
    const float* node_W     = (const float*)d_in[4];
    const float* node_b     = (const float*)d_in[5];
    const float* drone_W    = (const float*)d_in[6];
    const float* drone_b    = (const float*)d_in[7];
    // layers: convW, att_src, att_dst, convb, ln_g, ln_b
    const float* convW[2]   = {(const float*)d_in[8],  (const float*)d_in[14]};
    const float* att_src[2] = {(const float*)d_in[9],  (const float*)d_in[15]};
    const float* att_dst[2] = {(const float*)d_in[10], (const float*)d_in[16]};
    const float* convb[2]   = {(const float*)d_in[11], (const float*)d_in[17]};
    const float* ln_g[2]    = {(const float*)d_in[12], (const float*)d_in[18]};
    const float* ln_b[2]    = {(const float*)d_in[13], (const float*)d_in[19]};
    const float* out_W      = (const float*)d_in[20];
    const float* out_b      = (const float*)d_in[21];
    float* out = (float*)d_out;

    const int N = in_sizes[0] / 32;
    const int G = in_sizes[1] / 16;
    const int E = in_sizes[2] / 2;
    const int Etot = E + N;

    // workspace layout (256B aligned regions)
    char* base = (char*)d_ws;
    size_t off = 0;
    auto alloc = [&](size_t bytes) {
        char* p = base + off;
        off = (off + bytes + 255) & ~(size_t)255;
        return p;
    };
    float* h      = (float*)alloc((size_t)N * 64 * 4);
    float* xh     = (float*)alloc((size_t)N * 256 * 4);
    float* as_    = (float*)alloc((size_t)N * 4 * 4);
    float* ad_    = (float*)alloc((size_t)N * 4 * 4);
    float* dr     = (float*)alloc((size_t)G * 64 * 4);
    int*   deg    = (int*)alloc((size_t)N * 4);
    int*   rowptr = (int*)alloc((size_t)(N + 1) * 4);
    int*   cursor = (int*)alloc((size_t)N * 4);
    int*   csr    = (int*)alloc((size_t)Etot * 4);
    (void)ws_size;

    // node/drone embedding
    k_dr<<<cdiv((long long)G * 64, 256), 256, 0, stream>>>(drone_feat, drone_W, drone_b, dr, G);
    k_h0<<<cdiv((long long)N * 64, 256), 256, 0, stream>>>(x, batch, node_W, node_b, dr, h, N);

    // CSR build (dst-sorted, self loops included)
    k_deg_init<<<cdiv(N, 256), 256, 0, stream>>>(deg, N);
    k_count<<<cdiv(E, 256), 256, 0, stream>>>(edge_index, deg, E);
    k_scan<<<1, 1024, 0, stream>>>(deg, rowptr, cursor, N);
    k_scatter<<<cdiv(Etot, 256), 256, 0, stream>>>(edge_index, cursor, csr, E, N);

    // two GAT layers
    for (int l = 0; l < 2; ++l) {
        k_xh<<<cdiv(N, 8), 256, 0, stream>>>(h, convW[l], att_src[l], att_dst[l],
                                             xh, as_, ad_, N);
        k_gat<<<cdiv(N, 4), 256, 0, stream>>>(xh, as_, ad_, rowptr, csr, convb[l],
                                              ln_g[l], ln_b[l], h, N);
    }

    // output projection
    k_out<<<cdiv(N, 8), 256, 0, stream>>>(h, out_W, out_b, out, N);
}

// Round 2
// 1504.268 us; speedup vs baseline: 3.7152x; 3.7152x over previous
//
#include <hip/hip_runtime.h>
#include <math.h>

// N=100000, E=1600000, G=64, H=4, C=64, NODE_F=32, DRONE_F=16, OUT=32, L=2

#define NEG_SLOPE 0.2f
#define LN_EPS 1e-5f

// ---------------------------------------------------------------------------
__global__ void k_dr(const float* __restrict__ drone_feat,
                     const float* __restrict__ drone_W,
                     const float* __restrict__ drone_b,
                     float* __restrict__ dr, int G) {
    int i = blockIdx.x * blockDim.x + threadIdx.x;  // g*64 + c
    if (i >= G * 64) return;
    int g = i >> 6, c = i & 63;
    float acc = drone_b[c];
    const float* df = drone_feat + g * 16;
    const float* w  = drone_W + c * 16;
#pragma unroll
    for (int j = 0; j < 16; ++j) acc += df[j] * w[j];
    dr[i] = acc;
}

__global__ void k_h0(const float* __restrict__ x,
                     const int* __restrict__ batch,
                     const float* __restrict__ node_W,
                     const float* __restrict__ node_b,
                     const float* __restrict__ dr,
                     float* __restrict__ h, int N) {
    int i = blockIdx.x * blockDim.x + threadIdx.x;  // n*64 + c
    if (i >= N * 64) return;
    int n = i >> 6, c = i & 63;
    float acc = node_b[c] + dr[batch[n] * 64 + c];
    const float* xr = x + n * 32;
    const float* w  = node_W + c * 32;
#pragma unroll
    for (int k = 0; k < 32; ++k) acc += xr[k] * w[k];
    h[i] = acc;
}

__global__ void k_deg_init(int* __restrict__ deg, int N) {
    int i = blockIdx.x * blockDim.x + threadIdx.x;
    if (i < N) deg[i] = 1;
}

__global__ void k_count(const int* __restrict__ edge_index, int* __restrict__ deg, int E) {
    int i = blockIdx.x * blockDim.x + threadIdx.x;
    if (i < E) atomicAdd(deg + edge_index[E + i], 1);
}

__global__ void k_scan(const int* __restrict__ deg, int* __restrict__ rowptr,
                       int* __restrict__ cursor, int N) {
    __shared__ int part[1024];
    int t = threadIdx.x;
    int chunk = (N + 1023) >> 10;
    int start = t * chunk;
    int end = start + chunk; if (end > N) end = N; if (start > N) start = N;
    int sum = 0;
    for (int i = start; i < end; ++i) sum += deg[i];
    part[t] = sum;
    __syncthreads();
    for (int off = 1; off < 1024; off <<= 1) {
        int v = (t >= off) ? part[t - off] : 0;
        __syncthreads();
        part[t] += v;
        __syncthreads();
    }
    int base = part[t] - sum;  // exclusive prefix
    for (int i = start; i < end; ++i) {
        rowptr[i] = base;
        cursor[i] = base;
        base += deg[i];
    }
    if (t == 1023) rowptr[N] = part[1023];
}

__global__ void k_scatter(const int* __restrict__ edge_index, int* __restrict__ cursor,
                          int* __restrict__ csr, int E, int N) {
    int i = blockIdx.x * blockDim.x + threadIdx.x;
    if (i >= E + N) return;
    int s, d;
    if (i < E) { s = edge_index[i]; d = edge_index[E + i]; }
    else       { s = i - E; d = s; }
    int pos = atomicAdd(cursor + d, 1);
    csr[pos] = s;
}

// transpose convW [256 x 64] -> wt [64 x 256] so inner-loop weight loads coalesce
__global__ void k_wt(const float* __restrict__ convW, float* __restrict__ wt) {
    int i = blockIdx.x * blockDim.x + threadIdx.x;  // co*64 + k
    if (i >= 256 * 64) return;
    int co = i >> 6, k = i & 63;
    wt[k * 256 + co] = convW[i];
}

// xh[n][256] = h[n] @ convW.T via coalesced transposed weights.
// 16 nodes per 256-thread block; thread t owns output channel t for all 16.
// as/ad per-head dot products fused via per-wave shuffle reduce (wave w = head w).
#define TN 16
__global__ __launch_bounds__(256) void k_xh(
        const float* __restrict__ h, const float* __restrict__ wt,
        const float* __restrict__ att_src, const float* __restrict__ att_dst,
        float* __restrict__ xh, float* __restrict__ as_, float* __restrict__ ad_,
        int N) {
    __shared__ float hs[TN][64];
    int t = threadIdx.x;
    int n0 = blockIdx.x * TN;
    for (int i = t; i < TN * 64; i += 256) {
        int n = n0 + (i >> 6);
        hs[i >> 6][i & 63] = (n < N) ? h[(size_t)n * 64 + (i & 63)] : 0.f;
    }
    __syncthreads();
    float acc[TN];
#pragma unroll
    for (int j = 0; j < TN; ++j) acc[j] = 0.f;
    const float* wp = wt + t;
#pragma unroll 4
    for (int k4 = 0; k4 < 16; ++k4) {
        float w0 = wp[(k4 * 4 + 0) * 256];
        float w1 = wp[(k4 * 4 + 1) * 256];
        float w2 = wp[(k4 * 4 + 2) * 256];
        float w3 = wp[(k4 * 4 + 3) * 256];
#pragma unroll
        for (int j = 0; j < TN; ++j) {
            float4 hv = *(const float4*)&hs[j][k4 * 4];  // broadcast ds_read_b128
            acc[j] = fmaf(hv.x, w0, fmaf(hv.y, w1, fmaf(hv.z, w2, fmaf(hv.w, w3, acc[j]))));
        }
    }
    float asv = att_src[t], adv = att_dst[t];
    int head = t >> 6, lane = t & 63;
#pragma unroll
    for (int j = 0; j < TN; ++j) {
        int n = n0 + j;
        if (n < N) xh[(size_t)n * 256 + t] = acc[j];
        float vs = acc[j] * asv;
        float vd = acc[j] * adv;
#pragma unroll
        for (int off = 32; off >= 1; off >>= 1) {
            vs += __shfl_xor(vs, off, 64);
            vd += __shfl_xor(vd, off, 64);
        }
        if (lane == 0 && n < N) {
            as_[n * 4 + head] = vs;
            ad_[n * 4 + head] = vd;
        }
    }
}

// One wave per dst node: online softmax over incoming edges, fused
// head-mean + bias + LayerNorm + ReLU + residual (h += ...).
__global__ void k_gat(const float* __restrict__ xh, const float* __restrict__ as_,
                      const float* __restrict__ ad_, const int* __restrict__ rowptr,
                      const int* __restrict__ csr, const float* __restrict__ convb,
                      const float* __restrict__ ln_g, const float* __restrict__ ln_b,
                      float* __restrict__ h, int N) {
    int wid = threadIdx.x >> 6, lane = threadIdx.x & 63;
    int n = blockIdx.x * 4 + wid;
    if (n >= N) return;
    int r0 = rowptr[n], r1 = rowptr[n + 1];
    float4 adv = *(const float4*)(ad_ + (size_t)n * 4);
    float m0 = -INFINITY, m1 = -INFINITY, m2 = -INFINITY, m3 = -INFINITY;
    float s0 = 0.f, s1 = 0.f, s2 = 0.f, s3 = 0.f;
    float a0 = 0.f, a1 = 0.f, a2 = 0.f, a3 = 0.f;
    for (int i = r0; i < r1; ++i) {
        int src = csr[i];
        float4 asv = *(const float4*)(as_ + (size_t)src * 4);
        const float* xr = xh + (size_t)src * 256 + lane;
        float e, nm, sc, w;
        e = asv.x + adv.x; e = e > 0.f ? e : NEG_SLOPE * e;
        nm = fmaxf(m0, e); sc = __expf(m0 - nm); w = __expf(e - nm);
        s0 = s0 * sc + w; a0 = a0 * sc + w * xr[0];   m0 = nm;
        e = asv.y + adv.y; e = e > 0.f ? e : NEG_SLOPE * e;
        nm = fmaxf(m1, e); sc = __expf(m1 - nm); w = __expf(e - nm);
        s1 = s1 * sc + w; a1 = a1 * sc + w * xr[64];  m1 = nm;
        e = asv.z + adv.z; e = e > 0.f ? e : NEG_SLOPE * e;
        nm = fmaxf(m2, e); sc = __expf(m2 - nm); w = __expf(e - nm);
        s2 = s2 * sc + w; a2 = a2 * sc + w * xr[128]; m2 = nm;
        e = asv.w + adv.w; e = e > 0.f ? e : NEG_SLOPE * e;
        nm = fmaxf(m3, e); sc = __expf(m3 - nm); w = __expf(e - nm);
        s3 = s3 * sc + w; a3 = a3 * sc + w * xr[192]; m3 = nm;
    }
    float o = a0 / (s0 + 1e-16f) + a1 / (s1 + 1e-16f) +
              a2 / (s2 + 1e-16f) + a3 / (s3 + 1e-16f);
    o = 0.25f * o + convb[lane];
    float mu = o;
#pragma unroll
    for (int off = 32; off >= 1; off >>= 1) mu += __shfl_xor(mu, off, 64);
    mu *= (1.f / 64.f);
    float d = o - mu;
    float v = d * d;
#pragma unroll
    for (int off = 32; off >= 1; off >>= 1) v += __shfl_xor(v, off, 64);
    v *= (1.f / 64.f);
    float y = d * rsqrtf(v + LN_EPS) * ln_g[lane] + ln_b[lane];
    y = fmaxf(y, 0.f);
    h[(size_t)n * 64 + lane] += y;
}

__global__ void k_out(const float* __restrict__ h, const float* __restrict__ out_W,
                      const float* __restrict__ out_b, float* __restrict__ out, int N) {
    __shared__ float hs[8][64];
    int t = threadIdx.x;
    int n0 = blockIdx.x * 8;
    for (int i = t; i < 512; i += 256) {
        int n = n0 + (i >> 6);
        hs[i >> 6][i & 63] = (n < N) ? h[n * 64 + (i & 63)] : 0.f;
    }
    __syncthreads();
    int j = t >> 5, o = t & 31;
    int n = n0 + j;
    if (n >= N) return;
    float acc = out_b[o];
    const float* w = out_W + o * 64;
#pragma unroll
    for (int k = 0; k < 64; ++k) acc += hs[j][k] * w[k];
    out[n * 32 + o] = acc;
}

static inline unsigned cdiv(long long a, long long b) { return (unsigned)((a + b - 1) / b); }

extern "C" void kernel_launch(void* const* d_in, const int* in_sizes, int n_in,
                              void* d_out, int out_size, void* d_ws, size_t ws_size,
                              hipStream_t stream) {
    const float* x          = (const float*)d_in[0];
    const float* drone_feat = (const float*)d_in[1];
    const int*   edge_index = (const int*)d_in[2];
    const int*   batch      = (const int*)d_in[3];
    const float* node_W     = (const float*)d_in[4];
    const float* node_b     = (const float*)d_in[5];
    const float* drone_W    = (const float*)d_in[6];
    const float* drone_b    = (const float*)d_in[7];
    const float* convW[2]   = {(const float*)d_in[8],  (const float*)d_in[14]};
    const float* att_src[2] = {(const float*)d_in[9],  (const float*)d_in[15]};
    const float* att_dst[2] = {(const float*)d_in[10], (const float*)d_in[16]};
    const float* convb[2]   = {(const float*)d_in[11], (const float*)d_in[17]};
    const float* ln_g[2]    = {(const float*)d_in[12], (const float*)d_in[18]};
    const float* ln_b[2]    = {(const float*)d_in[13], (const float*)d_in[19]};
    const float* out_W      = (const float*)d_in[20];
    const float* out_b      = (const float*)d_in[21];
    float* out = (float*)d_out;

    const int N = in_sizes[0] / 32;
    const int G = in_sizes[1] / 16;
    const int E = in_sizes[2] / 2;
    const int Etot = E + N;

    char* base = (char*)d_ws;
    size_t off = 0;
    auto alloc = [&](size_t bytes) {
        char* p = base + off;
        off = (off + bytes + 255) & ~(size_t)255;
        return p;
    };
    float* h      = (float*)alloc((size_t)N * 64 * 4);
    float* xh     = (float*)alloc((size_t)N * 256 * 4);
    float* as_    = (float*)alloc((size_t)N * 4 * 4);
    float* ad_    = (float*)alloc((size_t)N * 4 * 4);
    float* dr     = (float*)alloc((size_t)G * 64 * 4);
    float* wt     = (float*)alloc((size_t)256 * 64 * 4);
    int*   deg    = (int*)alloc((size_t)N * 4);
    int*   rowptr = (int*)alloc((size_t)(N + 1) * 4);
    int*   cursor = (int*)alloc((size_t)N * 4);
    int*   csr    = (int*)alloc((size_t)Etot * 4);
    (void)ws_size;

    k_dr<<<cdiv((long long)G * 64, 256), 256, 0, stream>>>(drone_feat, drone_W, drone_b, dr, G);
    k_h0<<<cdiv((long long)N * 64, 256), 256, 0, stream>>>(x, batch, node_W, node_b, dr, h, N);

    k_deg_init<<<cdiv(N, 256), 256, 0, stream>>>(deg, N);
    k_count<<<cdiv(E, 256), 256, 0, stream>>>(edge_index, deg, E);
    k_scan<<<1, 1024, 0, stream>>>(deg, rowptr, cursor, N);
    k_scatter<<<cdiv(Etot, 256), 256, 0, stream>>>(edge_index, cursor, csr, E, N);

    for (int l = 0; l < 2; ++l) {
        k_wt<<<cdiv(256 * 64, 256), 256, 0, stream>>>(convW[l], wt);
        k_xh<<<cdiv(N, TN), 256, 0, stream>>>(h, wt, att_src[l], att_dst[l],
                                              xh, as_, ad_, N);
        k_gat<<<cdiv(N, 4), 256, 0, stream>>>(xh, as_, ad_, rowptr, csr, convb[l],
                                              ln_g[l], ln_b[l], h, N);
    }

    k_out<<<cdiv(N, 8), 256, 0, stream>>>(h, out_W, out_b, out, N);
}

// Round 3
// 1346.607 us; speedup vs baseline: 4.1502x; 1.1171x over previous
//
#include <hip/hip_runtime.h>
#include <hip/hip_bf16.h>
#include <math.h>

// N=100000, E=1600000, G=64, H=4, C=64, NODE_F=32, DRONE_F=16, OUT=32, L=2

#define NEG_SLOPE 0.2f
#define LN_EPS 1e-5f

// ---------------------------------------------------------------------------
__global__ void k_dr(const float* __restrict__ drone_feat,
                     const float* __restrict__ drone_W,
                     const float* __restrict__ drone_b,
                     float* __restrict__ dr, int G) {
    int i = blockIdx.x * blockDim.x + threadIdx.x;  // g*64 + c
    if (i >= G * 64) return;
    int g = i >> 6, c = i & 63;
    float acc = drone_b[c];
    const float* df = drone_feat + g * 16;
    const float* w  = drone_W + c * 16;
#pragma unroll
    for (int j = 0; j < 16; ++j) acc += df[j] * w[j];
    dr[i] = acc;
}

__global__ void k_h0(const float* __restrict__ x,
                     const int* __restrict__ batch,
                     const float* __restrict__ node_W,
                     const float* __restrict__ node_b,
                     const float* __restrict__ dr,
                     float* __restrict__ h, int N) {
    int i = blockIdx.x * blockDim.x + threadIdx.x;  // n*64 + c
    if (i >= N * 64) return;
    int n = i >> 6, c = i & 63;
    float acc = node_b[c] + dr[batch[n] * 64 + c];
    const float* xr = x + n * 32;
    const float* w  = node_W + c * 32;
#pragma unroll
    for (int k = 0; k < 32; ++k) acc += xr[k] * w[k];
    h[i] = acc;
}

__global__ void k_deg_init(int* __restrict__ deg, int N) {
    int i = blockIdx.x * blockDim.x + threadIdx.x;
    if (i < N) deg[i] = 1;
}

__global__ void k_count(const int* __restrict__ edge_index, int* __restrict__ deg, int E) {
    int i = blockIdx.x * blockDim.x + threadIdx.x;
    if (i < E) atomicAdd(deg + edge_index[E + i], 1);
}

__global__ void k_scan(const int* __restrict__ deg, int* __restrict__ rowptr,
                       int* __restrict__ cursor, int N) {
    __shared__ int part[1024];
    int t = threadIdx.x;
    int chunk = (N + 1023) >> 10;
    int start = t * chunk;
    int end = start + chunk; if (end > N) end = N; if (start > N) start = N;
    int sum = 0;
    for (int i = start; i < end; ++i) sum += deg[i];
    part[t] = sum;
    __syncthreads();
    for (int off = 1; off < 1024; off <<= 1) {
        int v = (t >= off) ? part[t - off] : 0;
        __syncthreads();
        part[t] += v;
        __syncthreads();
    }
    int base = part[t] - sum;  // exclusive prefix
    for (int i = start; i < end; ++i) {
        rowptr[i] = base;
        cursor[i] = base;
        base += deg[i];
    }
    if (t == 1023) rowptr[N] = part[1023];
}

__global__ void k_scatter(const int* __restrict__ edge_index, int* __restrict__ cursor,
                          int* __restrict__ csr, int E, int N) {
    int i = blockIdx.x * blockDim.x + threadIdx.x;
    if (i >= E + N) return;
    int s, d;
    if (i < E) { s = edge_index[i]; d = edge_index[E + i]; }
    else       { s = i - E; d = s; }
    int pos = atomicAdd(cursor + d, 1);
    csr[pos] = s;
}

// transpose convW [256 x 64] -> wt [64 x 256] so inner-loop weight loads coalesce
__global__ void k_wt(const float* __restrict__ convW, float* __restrict__ wt) {
    int i = blockIdx.x * blockDim.x + threadIdx.x;  // co*64 + k
    if (i >= 256 * 64) return;
    int co = i >> 6, k = i & 63;
    wt[k * 256 + co] = convW[i];
}

// xh[n][256] = h[n] @ convW.T (stored bf16); as/ad[n][h] fused via shuffle reduce.
#define TN 16
__global__ __launch_bounds__(256) void k_xh(
        const float* __restrict__ h, const float* __restrict__ wt,
        const float* __restrict__ att_src, const float* __restrict__ att_dst,
        __hip_bfloat16* __restrict__ xh, float* __restrict__ as_, float* __restrict__ ad_,
        int N) {
    __shared__ float hs[TN][64];
    int t = threadIdx.x;
    int n0 = blockIdx.x * TN;
    for (int i = t; i < TN * 64; i += 256) {
        int n = n0 + (i >> 6);
        hs[i >> 6][i & 63] = (n < N) ? h[(size_t)n * 64 + (i & 63)] : 0.f;
    }
    __syncthreads();
    float acc[TN];
#pragma unroll
    for (int j = 0; j < TN; ++j) acc[j] = 0.f;
    const float* wp = wt + t;
#pragma unroll 4
    for (int k4 = 0; k4 < 16; ++k4) {
        float w0 = wp[(k4 * 4 + 0) * 256];
        float w1 = wp[(k4 * 4 + 1) * 256];
        float w2 = wp[(k4 * 4 + 2) * 256];
        float w3 = wp[(k4 * 4 + 3) * 256];
#pragma unroll
        for (int j = 0; j < TN; ++j) {
            float4 hv = *(const float4*)&hs[j][k4 * 4];  // broadcast ds_read_b128
            acc[j] = fmaf(hv.x, w0, fmaf(hv.y, w1, fmaf(hv.z, w2, fmaf(hv.w, w3, acc[j]))));
        }
    }
    float asv = att_src[t], adv = att_dst[t];
    int head = t >> 6, lane = t & 63;
#pragma unroll
    for (int j = 0; j < TN; ++j) {
        int n = n0 + j;
        if (n < N) xh[(size_t)n * 256 + t] = __float2bfloat16(acc[j]);
        float vs = acc[j] * asv;
        float vd = acc[j] * adv;
#pragma unroll
        for (int off = 32; off >= 1; off >>= 1) {
            vs += __shfl_xor(vs, off, 64);
            vd += __shfl_xor(vd, off, 64);
        }
        if (lane == 0 && n < N) {
            as_[n * 4 + head] = vs;
            ad_[n * 4 + head] = vd;
        }
    }
}

// One wave per dst node. Lane l owns 4 channels (c4 = (l&15)*4) of head (l>>4).
// No max-subtraction (e bounded, exp safe). One exp per 16-lane group per edge.
// Head-mean via shfl_xor(16,32); LN within 16-lane groups; lanes<16 write back.
__global__ __launch_bounds__(256) void k_gat(
        const __hip_bfloat16* __restrict__ xh, const float* __restrict__ as_,
        const float* __restrict__ ad_, const int* __restrict__ rowptr,
        const int* __restrict__ csr, const float* __restrict__ convb,
        const float* __restrict__ ln_g, const float* __restrict__ ln_b,
        float* __restrict__ h, int N) {
    int wid = threadIdx.x >> 6, lane = threadIdx.x & 63;
    int n = blockIdx.x * 4 + wid;
    if (n >= N) return;
    int head = lane >> 4;
    int c4 = (lane & 15) * 4;
    int r0 = rowptr[n], r1 = rowptr[n + 1];
    float adv = ad_[n * 4 + head];
    float s = 0.f;
    float ax = 0.f, ay = 0.f, az = 0.f, aw = 0.f;
    int src = csr[r0];  // deg >= 1 (self loop)
    for (int i = r0; i < r1; ++i) {
        int nsrc = (i + 1 < r1) ? csr[i + 1] : 0;
        float e = as_[(size_t)src * 4 + head] + adv;
        e = e > 0.f ? e : NEG_SLOPE * e;
        float w = __expf(e);
        s += w;
        // 4 bf16 channels at element index src*256 + lane*4 (8B aligned)
        uint2 p = *(const uint2*)(xh + (size_t)src * 256 + lane * 4);
        float x0 = __uint_as_float(p.x << 16);
        float x1 = __uint_as_float(p.x & 0xffff0000u);
        float x2 = __uint_as_float(p.y << 16);
        float x3 = __uint_as_float(p.y & 0xffff0000u);
        ax = fmaf(w, x0, ax);
        ay = fmaf(w, x1, ay);
        az = fmaf(w, x2, az);
        aw = fmaf(w, x3, aw);
        src = nsrc;
    }
    float inv = 1.f / (s + 1e-16f);
    ax *= inv; ay *= inv; az *= inv; aw *= inv;
    // sum over 4 heads: lanes {l, l^16, l^32, l^48} hold same channels
#pragma unroll
    for (int off = 16; off <= 32; off <<= 1) {
        ax += __shfl_xor(ax, off, 64);
        ay += __shfl_xor(ay, off, 64);
        az += __shfl_xor(az, off, 64);
        aw += __shfl_xor(aw, off, 64);
    }
    float4 cb = *(const float4*)(convb + c4);
    float ox = 0.25f * ax + cb.x;
    float oy = 0.25f * ay + cb.y;
    float oz = 0.25f * az + cb.z;
    float ow = 0.25f * aw + cb.w;
    // LayerNorm over 64 channels, held as 4/lane across 16-lane groups
    float part = ox + oy + oz + ow;
#pragma unroll
    for (int off = 1; off <= 8; off <<= 1) part += __shfl_xor(part, off, 64);
    float mu = part * (1.f / 64.f);
    float dx = ox - mu, dy = oy - mu, dz = oz - mu, dw = ow - mu;
    float vs = dx * dx + dy * dy + dz * dz + dw * dw;
#pragma unroll
    for (int off = 1; off <= 8; off <<= 1) vs += __shfl_xor(vs, off, 64);
    float rstd = rsqrtf(vs * (1.f / 64.f) + LN_EPS);
    float4 g = *(const float4*)(ln_g + c4);
    float4 b = *(const float4*)(ln_b + c4);
    if (lane < 16) {
        float4* hp = (float4*)(h + (size_t)n * 64 + c4);
        float4 hv = *hp;
        hv.x += fmaxf(dx * rstd * g.x + b.x, 0.f);
        hv.y += fmaxf(dy * rstd * g.y + b.y, 0.f);
        hv.z += fmaxf(dz * rstd * g.z + b.z, 0.f);
        hv.w += fmaxf(dw * rstd * g.w + b.w, 0.f);
        *hp = hv;
    }
}

__global__ void k_out(const float* __restrict__ h, const float* __restrict__ out_W,
                      const float* __restrict__ out_b, float* __restrict__ out, int N) {
    __shared__ float hs[8][64];
    int t = threadIdx.x;
    int n0 = blockIdx.x * 8;
    for (int i = t; i < 512; i += 256) {
        int n = n0 + (i >> 6);
        hs[i >> 6][i & 63] = (n < N) ? h[n * 64 + (i & 63)] : 0.f;
    }
    __syncthreads();
    int j = t >> 5, o = t & 31;
    int n = n0 + j;
    if (n >= N) return;
    float acc = out_b[o];
    const float* w = out_W + o * 64;
#pragma unroll
    for (int k = 0; k < 64; ++k) acc += hs[j][k] * w[k];
    out[n * 32 + o] = acc;
}

static inline unsigned cdiv(long long a, long long b) { return (unsigned)((a + b - 1) / b); }

extern "C" void kernel_launch(void* const* d_in, const int* in_sizes, int n_in,
                              void* d_out, int out_size, void* d_ws, size_t ws_size,
                              hipStream_t stream) {
    const float* x          = (const float*)d_in[0];
    const float* drone_feat = (const float*)d_in[1];
    const int*   edge_index = (const int*)d_in[2];
    const int*   batch      = (const int*)d_in[3];
    const float* node_W     = (const float*)d_in[4];
    const float* node_b     = (const float*)d_in[5];
    const float* drone_W    = (const float*)d_in[6];
    const float* drone_b    = (const float*)d_in[7];
    const float* convW[2]   = {(const float*)d_in[8],  (const float*)d_in[14]};
    const float* att_src[2] = {(const float*)d_in[9],  (const float*)d_in[15]};
    const float* att_dst[2] = {(const float*)d_in[10], (const float*)d_in[16]};
    const float* convb[2]   = {(const float*)d_in[11], (const float*)d_in[17]};
    const float* ln_g[2]    = {(const float*)d_in[12], (const float*)d_in[18]};
    const float* ln_b[2]    = {(const float*)d_in[13], (const float*)d_in[19]};
    const float* out_W      = (const float*)d_in[20];
    const float* out_b      = (const float*)d_in[21];
    float* out = (float*)d_out;

    const int N = in_sizes[0] / 32;
    const int G = in_sizes[1] / 16;
    const int E = in_sizes[2] / 2;
    const int Etot = E + N;

    char* base = (char*)d_ws;
    size_t off = 0;
    auto alloc = [&](size_t bytes) {
        char* p = base + off;
        off = (off + bytes + 255) & ~(size_t)255;
        return p;
    };
    float*           h      = (float*)alloc((size_t)N * 64 * 4);
    __hip_bfloat16*  xh     = (__hip_bfloat16*)alloc((size_t)N * 256 * 2);
    float*           as_    = (float*)alloc((size_t)N * 4 * 4);
    float*           ad_    = (float*)alloc((size_t)N * 4 * 4);
    float*           dr     = (float*)alloc((size_t)G * 64 * 4);
    float*           wt     = (float*)alloc((size_t)256 * 64 * 4);
    int*             deg    = (int*)alloc((size_t)N * 4);
    int*             rowptr = (int*)alloc((size_t)(N + 1) * 4);
    int*             cursor = (int*)alloc((size_t)N * 4);
    int*             csr    = (int*)alloc((size_t)Etot * 4);
    (void)ws_size;

    k_dr<<<cdiv((long long)G * 64, 256), 256, 0, stream>>>(drone_feat, drone_W, drone_b, dr, G);
    k_h0<<<cdiv((long long)N * 64, 256), 256, 0, stream>>>(x, batch, node_W, node_b, dr, h, N);

    k_deg_init<<<cdiv(N, 256), 256, 0, stream>>>(deg, N);
    k_count<<<cdiv(E, 256), 256, 0, stream>>>(edge_index, deg, E);
    k_scan<<<1, 1024, 0, stream>>>(deg, rowptr, cursor, N);
    k_scatter<<<cdiv(Etot, 256), 256, 0, stream>>>(edge_index, cursor, csr, E, N);

    for (int l = 0; l < 2; ++l) {
        k_wt<<<cdiv(256 * 64, 256), 256, 0, stream>>>(convW[l], wt);
        k_xh<<<cdiv(N, TN), 256, 0, stream>>>(h, wt, att_src[l], att_dst[l],
                                              xh, as_, ad_, N);
        k_gat<<<cdiv(N, 4), 256, 0, stream>>>(xh, as_, ad_, rowptr, csr, convb[l],
                                              ln_g[l], ln_b[l], h, N);
    }

    k_out<<<cdiv(N, 8), 256, 0, stream>>>(h, out_W, out_b, out, N);
}

// Round 4
// 1114.082 us; speedup vs baseline: 5.0164x; 1.2087x over previous
//
#include <hip/hip_runtime.h>
#include <hip/hip_bf16.h>
#include <math.h>

// N=100000, E=1600000, G=64, H=4, C=64, NODE_F=32, DRONE_F=16, OUT=32, L=2

#define NEG_SLOPE 0.2f
#define LN_EPS 1e-5f

// ---------------------------------------------------------------------------
__global__ void k_dr(const float* __restrict__ drone_feat,
                     const float* __restrict__ drone_W,
                     const float* __restrict__ drone_b,
                     float* __restrict__ dr, int G) {
    int i = blockIdx.x * blockDim.x + threadIdx.x;  // g*64 + c
    if (i >= G * 64) return;
    int g = i >> 6, c = i & 63;
    float acc = drone_b[c];
    const float* df = drone_feat + g * 16;
    const float* w  = drone_W + c * 16;
#pragma unroll
    for (int j = 0; j < 16; ++j) acc += df[j] * w[j];
    dr[i] = acc;
}

__global__ void k_h0(const float* __restrict__ x,
                     const int* __restrict__ batch,
                     const float* __restrict__ node_W,
                     const float* __restrict__ node_b,
                     const float* __restrict__ dr,
                     float* __restrict__ h, int N) {
    int i = blockIdx.x * blockDim.x + threadIdx.x;  // n*64 + c
    if (i >= N * 64) return;
    int n = i >> 6, c = i & 63;
    float acc = node_b[c] + dr[batch[n] * 64 + c];
    const float* xr = x + n * 32;
    const float* w  = node_W + c * 32;
#pragma unroll
    for (int k = 0; k < 32; ++k) acc += xr[k] * w[k];
    h[i] = acc;
}

__global__ void k_deg_init(int* __restrict__ deg, int N) {
    int i = blockIdx.x * blockDim.x + threadIdx.x;
    if (i < N) deg[i] = 1;
}

__global__ void k_count(const int* __restrict__ edge_index, int* __restrict__ deg, int E) {
    int i = blockIdx.x * blockDim.x + threadIdx.x;
    if (i < E) atomicAdd(deg + edge_index[E + i], 1);
}

// --- hierarchical scan of deg -> rowptr/cursor (replaces single-block k_scan)
// A: per-block (1024 elems) sums
__global__ __launch_bounds__(256) void k_bsum(const int* __restrict__ deg,
                                              int* __restrict__ bsum, int N) {
    int t = threadIdx.x;
    int base = blockIdx.x * 1024 + t * 4;
    int s = 0;
#pragma unroll
    for (int j = 0; j < 4; ++j) s += (base + j < N) ? deg[base + j] : 0;
    int lane = t & 63, wid = t >> 6;
#pragma unroll
    for (int off = 32; off >= 1; off >>= 1) s += __shfl_xor(s, off, 64);
    __shared__ int ws[4];
    if (lane == 0) ws[wid] = s;
    __syncthreads();
    if (t == 0) bsum[blockIdx.x] = ws[0] + ws[1] + ws[2] + ws[3];
}

// B: one block exclusive-scans bsum in place (nb <= 256)
__global__ __launch_bounds__(256) void k_bscan(int* __restrict__ bsum, int nb) {
    int t = threadIdx.x;
    int s = (t < nb) ? bsum[t] : 0;
    int lane = t & 63, wid = t >> 6;
    int v = s;
#pragma unroll
    for (int off = 1; off < 64; off <<= 1) {
        int u = __shfl_up(v, off, 64);
        if (lane >= off) v += u;
    }
    __shared__ int wsum[4];
    if (lane == 63) wsum[wid] = v;
    __syncthreads();
    int woff = 0;
    for (int w = 0; w < wid; ++w) woff += wsum[w];
    if (t < nb) bsum[t] = woff + v - s;  // exclusive block offset
}

// C: per-block local scan + block offset -> rowptr/cursor
__global__ __launch_bounds__(256) void k_fill(const int* __restrict__ deg,
                                              const int* __restrict__ boff,
                                              int* __restrict__ rowptr,
                                              int* __restrict__ cursor,
                                              int N, int Etot) {
    int t = threadIdx.x;
    int base = blockIdx.x * 1024 + t * 4;
    int d[4];
#pragma unroll
    for (int j = 0; j < 4; ++j) d[j] = (base + j < N) ? deg[base + j] : 0;
    int s = d[0] + d[1] + d[2] + d[3];
    int lane = t & 63, wid = t >> 6;
    int v = s;
#pragma unroll
    for (int off = 1; off < 64; off <<= 1) {
        int u = __shfl_up(v, off, 64);
        if (lane >= off) v += u;
    }
    __shared__ int wsum[4];
    if (lane == 63) wsum[wid] = v;
    __syncthreads();
    int woff = 0;
    for (int w = 0; w < wid; ++w) woff += wsum[w];
    int off0 = boff[blockIdx.x] + woff + v - s;  // exclusive prefix for this thread
#pragma unroll
    for (int j = 0; j < 4; ++j) {
        int idx = base + j;
        if (idx < N) { rowptr[idx] = off0; cursor[idx] = off0; }
        off0 += d[j];
    }
    if (blockIdx.x == 0 && t == 0) rowptr[N] = Etot;
}

__global__ void k_scatter(const int* __restrict__ edge_index, int* __restrict__ cursor,
                          int* __restrict__ csr, int E, int N) {
    int i = blockIdx.x * blockDim.x + threadIdx.x;
    if (i >= E + N) return;
    int s, d;
    if (i < E) { s = edge_index[i]; d = edge_index[E + i]; }
    else       { s = i - E; d = s; }
    int pos = atomicAdd(cursor + d, 1);
    csr[pos] = s;
}

// transpose convW [256 x 64] -> wt [64 x 256] so inner-loop weight loads coalesce
__global__ void k_wt(const float* __restrict__ convW, float* __restrict__ wt) {
    int i = blockIdx.x * blockDim.x + threadIdx.x;  // co*64 + k
    if (i >= 256 * 64) return;
    int co = i >> 6, k = i & 63;
    wt[k * 256 + co] = convW[i];
}

// xh[n][256] = h[n] @ convW.T (stored bf16); as/ad[n][h] fused via shuffle reduce.
#define TN 16
__global__ __launch_bounds__(256) void k_xh(
        const float* __restrict__ h, const float* __restrict__ wt,
        const float* __restrict__ att_src, const float* __restrict__ att_dst,
        __hip_bfloat16* __restrict__ xh, float* __restrict__ as_, float* __restrict__ ad_,
        int N) {
    __shared__ float hs[TN][64];
    int t = threadIdx.x;
    int n0 = blockIdx.x * TN;
    for (int i = t; i < TN * 64; i += 256) {
        int n = n0 + (i >> 6);
        hs[i >> 6][i & 63] = (n < N) ? h[(size_t)n * 64 + (i & 63)] : 0.f;
    }
    __syncthreads();
    float acc[TN];
#pragma unroll
    for (int j = 0; j < TN; ++j) acc[j] = 0.f;
    const float* wp = wt + t;
#pragma unroll 4
    for (int k4 = 0; k4 < 16; ++k4) {
        float w0 = wp[(k4 * 4 + 0) * 256];
        float w1 = wp[(k4 * 4 + 1) * 256];
        float w2 = wp[(k4 * 4 + 2) * 256];
        float w3 = wp[(k4 * 4 + 3) * 256];
#pragma unroll
        for (int j = 0; j < TN; ++j) {
            float4 hv = *(const float4*)&hs[j][k4 * 4];  // broadcast ds_read_b128
            acc[j] = fmaf(hv.x, w0, fmaf(hv.y, w1, fmaf(hv.z, w2, fmaf(hv.w, w3, acc[j]))));
        }
    }
    float asv = att_src[t], adv = att_dst[t];
    int head = t >> 6, lane = t & 63;
#pragma unroll
    for (int j = 0; j < TN; ++j) {
        int n = n0 + j;
        if (n < N) xh[(size_t)n * 256 + t] = __float2bfloat16(acc[j]);
        float vs = acc[j] * asv;
        float vd = acc[j] * adv;
#pragma unroll
        for (int off = 32; off >= 1; off >>= 1) {
            vs += __shfl_xor(vs, off, 64);
            vd += __shfl_xor(vd, off, 64);
        }
        if (lane == 0 && n < N) {
            as_[n * 4 + head] = vs;
            ad_[n * 4 + head] = vd;
        }
    }
}

// One wave per dst node. Lane l owns 4 channels (c4 = (l&15)*4) of head (l>>4).
__global__ __launch_bounds__(256) void k_gat(
        const __hip_bfloat16* __restrict__ xh, const float* __restrict__ as_,
        const float* __restrict__ ad_, const int* __restrict__ rowptr,
        const int* __restrict__ csr, const float* __restrict__ convb,
        const float* __restrict__ ln_g, const float* __restrict__ ln_b,
        float* __restrict__ h, int N) {
    int wid = threadIdx.x >> 6, lane = threadIdx.x & 63;
    int n = blockIdx.x * 4 + wid;
    if (n >= N) return;
    int head = lane >> 4;
    int c4 = (lane & 15) * 4;
    int r0 = rowptr[n], r1 = rowptr[n + 1];
    float adv = ad_[n * 4 + head];
    float s = 0.f;
    float ax = 0.f, ay = 0.f, az = 0.f, aw = 0.f;
    int src = csr[r0];  // deg >= 1 (self loop)
    for (int i = r0; i < r1; ++i) {
        int nsrc = (i + 1 < r1) ? csr[i + 1] : 0;
        float e = as_[(size_t)src * 4 + head] + adv;
        e = e > 0.f ? e : NEG_SLOPE * e;
        float w = __expf(e);
        s += w;
        uint2 p = *(const uint2*)(xh + (size_t)src * 256 + lane * 4);
        float x0 = __uint_as_float(p.x << 16);
        float x1 = __uint_as_float(p.x & 0xffff0000u);
        float x2 = __uint_as_float(p.y << 16);
        float x3 = __uint_as_float(p.y & 0xffff0000u);
        ax = fmaf(w, x0, ax);
        ay = fmaf(w, x1, ay);
        az = fmaf(w, x2, az);
        aw = fmaf(w, x3, aw);
        src = nsrc;
    }
    float inv = 1.f / (s + 1e-16f);
    ax *= inv; ay *= inv; az *= inv; aw *= inv;
#pragma unroll
    for (int off = 16; off <= 32; off <<= 1) {
        ax += __shfl_xor(ax, off, 64);
        ay += __shfl_xor(ay, off, 64);
        az += __shfl_xor(az, off, 64);
        aw += __shfl_xor(aw, off, 64);
    }
    float4 cb = *(const float4*)(convb + c4);
    float ox = 0.25f * ax + cb.x;
    float oy = 0.25f * ay + cb.y;
    float oz = 0.25f * az + cb.z;
    float ow = 0.25f * aw + cb.w;
    float part = ox + oy + oz + ow;
#pragma unroll
    for (int off = 1; off <= 8; off <<= 1) part += __shfl_xor(part, off, 64);
    float mu = part * (1.f / 64.f);
    float dx = ox - mu, dy = oy - mu, dz = oz - mu, dw = ow - mu;
    float vs = dx * dx + dy * dy + dz * dz + dw * dw;
#pragma unroll
    for (int off = 1; off <= 8; off <<= 1) vs += __shfl_xor(vs, off, 64);
    float rstd = rsqrtf(vs * (1.f / 64.f) + LN_EPS);
    float4 g = *(const float4*)(ln_g + c4);
    float4 b = *(const float4*)(ln_b + c4);
    if (lane < 16) {
        float4* hp = (float4*)(h + (size_t)n * 64 + c4);
        float4 hv = *hp;
        hv.x += fmaxf(dx * rstd * g.x + b.x, 0.f);
        hv.y += fmaxf(dy * rstd * g.y + b.y, 0.f);
        hv.z += fmaxf(dz * rstd * g.z + b.z, 0.f);
        hv.w += fmaxf(dw * rstd * g.w + b.w, 0.f);
        *hp = hv;
    }
}

__global__ void k_out(const float* __restrict__ h, const float* __restrict__ out_W,
                      const float* __restrict__ out_b, float* __restrict__ out, int N) {
    __shared__ float hs[8][64];
    int t = threadIdx.x;
    int n0 = blockIdx.x * 8;
    for (int i = t; i < 512; i += 256) {
        int n = n0 + (i >> 6);
        hs[i >> 6][i & 63] = (n < N) ? h[n * 64 + (i & 63)] : 0.f;
    }
    __syncthreads();
    int j = t >> 5, o = t & 31;
    int n = n0 + j;
    if (n >= N) return;
    float acc = out_b[o];
    const float* w = out_W + o * 64;
#pragma unroll
    for (int k = 0; k < 64; ++k) acc += hs[j][k] * w[k];
    out[n * 32 + o] = acc;
}

static inline unsigned cdiv(long long a, long long b) { return (unsigned)((a + b - 1) / b); }

extern "C" void kernel_launch(void* const* d_in, const int* in_sizes, int n_in,
                              void* d_out, int out_size, void* d_ws, size_t ws_size,
                              hipStream_t stream) {
    const float* x          = (const float*)d_in[0];
    const float* drone_feat = (const float*)d_in[1];
    const int*   edge_index = (const int*)d_in[2];
    const int*   batch      = (const int*)d_in[3];
    const float* node_W     = (const float*)d_in[4];
    const float* node_b     = (const float*)d_in[5];
    const float* drone_W    = (const float*)d_in[6];
    const float* drone_b    = (const float*)d_in[7];
    const float* convW[2]   = {(const float*)d_in[8],  (const float*)d_in[14]};
    const float* att_src[2] = {(const float*)d_in[9],  (const float*)d_in[15]};
    const float* att_dst[2] = {(const float*)d_in[10], (const float*)d_in[16]};
    const float* convb[2]   = {(const float*)d_in[11], (const float*)d_in[17]};
    const float* ln_g[2]    = {(const float*)d_in[12], (const float*)d_in[18]};
    const float* ln_b[2]    = {(const float*)d_in[13], (const float*)d_in[19]};
    const float* out_W      = (const float*)d_in[20];
    const float* out_b      = (const float*)d_in[21];
    float* out = (float*)d_out;

    const int N = in_sizes[0] / 32;
    const int G = in_sizes[1] / 16;
    const int E = in_sizes[2] / 2;
    const int Etot = E + N;
    const int NB = cdiv(N, 1024);  // blocks for hierarchical scan (<=256)

    char* base = (char*)d_ws;
    size_t off = 0;
    auto alloc = [&](size_t bytes) {
        char* p = base + off;
        off = (off + bytes + 255) & ~(size_t)255;
        return p;
    };
    float*           h      = (float*)alloc((size_t)N * 64 * 4);
    __hip_bfloat16*  xh     = (__hip_bfloat16*)alloc((size_t)N * 256 * 2);
    float*           as_    = (float*)alloc((size_t)N * 4 * 4);
    float*           ad_    = (float*)alloc((size_t)N * 4 * 4);
    float*           dr     = (float*)alloc((size_t)G * 64 * 4);
    float*           wt     = (float*)alloc((size_t)256 * 64 * 4);
    int*             deg    = (int*)alloc((size_t)N * 4);
    int*             rowptr = (int*)alloc((size_t)(N + 1) * 4);
    int*             cursor = (int*)alloc((size_t)N * 4);
    int*             csr    = (int*)alloc((size_t)Etot * 4);
    int*             bsum   = (int*)alloc((size_t)256 * 4);
    (void)ws_size;

    k_dr<<<cdiv((long long)G * 64, 256), 256, 0, stream>>>(drone_feat, drone_W, drone_b, dr, G);
    k_h0<<<cdiv((long long)N * 64, 256), 256, 0, stream>>>(x, batch, node_W, node_b, dr, h, N);

    k_deg_init<<<cdiv(N, 256), 256, 0, stream>>>(deg, N);
    k_count<<<cdiv(E, 256), 256, 0, stream>>>(edge_index, deg, E);
    k_bsum<<<NB, 256, 0, stream>>>(deg, bsum, N);
    k_bscan<<<1, 256, 0, stream>>>(bsum, NB);
    k_fill<<<NB, 256, 0, stream>>>(deg, bsum, rowptr, cursor, N, Etot);
    k_scatter<<<cdiv(Etot, 256), 256, 0, stream>>>(edge_index, cursor, csr, E, N);

    for (int l = 0; l < 2; ++l) {
        k_wt<<<cdiv(256 * 64, 256), 256, 0, stream>>>(convW[l], wt);
        k_xh<<<cdiv(N, TN), 256, 0, stream>>>(h, wt, att_src[l], att_dst[l],
                                              xh, as_, ad_, N);
        k_gat<<<cdiv(N, 4), 256, 0, stream>>>(xh, as_, ad_, rowptr, csr, convb[l],
                                              ln_g[l], ln_b[l], h, N);
    }

    k_out<<<cdiv(N, 8), 256, 0, stream>>>(h, out_W, out_b, out, N);
}

// Round 5
// 997.331 us; speedup vs baseline: 5.6036x; 1.1171x over previous
//
#include <hip/hip_runtime.h>
#include <hip/hip_bf16.h>
#include <math.h>

// N=100000, E=1600000, G=64, H=4, C=64, NODE_F=32, DRONE_F=16, OUT=32, L=2

#define NEG_SLOPE 0.2f
#define LN_EPS 1e-5f

// ---------------------------------------------------------------------------
__global__ void k_dr(const float* __restrict__ drone_feat,
                     const float* __restrict__ drone_W,
                     const float* __restrict__ drone_b,
                     float* __restrict__ dr, int G) {
    int i = blockIdx.x * blockDim.x + threadIdx.x;  // g*64 + c
    if (i >= G * 64) return;
    int g = i >> 6, c = i & 63;
    float acc = drone_b[c];
    const float* df = drone_feat + g * 16;
    const float* w  = drone_W + c * 16;
#pragma unroll
    for (int j = 0; j < 16; ++j) acc += df[j] * w[j];
    dr[i] = acc;
}

__global__ void k_h0(const float* __restrict__ x,
                     const int* __restrict__ batch,
                     const float* __restrict__ node_W,
                     const float* __restrict__ node_b,
                     const float* __restrict__ dr,
                     float* __restrict__ h, int N) {
    int i = blockIdx.x * blockDim.x + threadIdx.x;  // n*64 + c
    if (i >= N * 64) return;
    int n = i >> 6, c = i & 63;
    float acc = node_b[c] + dr[batch[n] * 64 + c];
    const float* xr = x + n * 32;
    const float* w  = node_W + c * 32;
#pragma unroll
    for (int k = 0; k < 32; ++k) acc += xr[k] * w[k];
    h[i] = acc;
}

__global__ void k_count(const int* __restrict__ edge_index, int* __restrict__ deg, int E) {
    int i = blockIdx.x * blockDim.x + threadIdx.x;
    if (i < E) atomicAdd(deg + edge_index[E + i], 1);
}

// --- hierarchical scan of (deg+1) -> rowptr/cursor. deg holds real-edge counts
// (memset 0 + k_count); the +1 self loop is implicit in bsum/fill.
__global__ __launch_bounds__(256) void k_bsum(const int* __restrict__ deg,
                                              int* __restrict__ bsum, int N) {
    int t = threadIdx.x;
    int base = blockIdx.x * 1024 + t * 4;
    int s = 0;
#pragma unroll
    for (int j = 0; j < 4; ++j) s += (base + j < N) ? (deg[base + j] + 1) : 0;
    int lane = t & 63, wid = t >> 6;
#pragma unroll
    for (int off = 32; off >= 1; off >>= 1) s += __shfl_xor(s, off, 64);
    __shared__ int ws[4];
    if (lane == 0) ws[wid] = s;
    __syncthreads();
    if (t == 0) bsum[blockIdx.x] = ws[0] + ws[1] + ws[2] + ws[3];
}

__global__ __launch_bounds__(256) void k_bscan(int* __restrict__ bsum, int nb) {
    int t = threadIdx.x;
    int s = (t < nb) ? bsum[t] : 0;
    int lane = t & 63, wid = t >> 6;
    int v = s;
#pragma unroll
    for (int off = 1; off < 64; off <<= 1) {
        int u = __shfl_up(v, off, 64);
        if (lane >= off) v += u;
    }
    __shared__ int wsum[4];
    if (lane == 63) wsum[wid] = v;
    __syncthreads();
    int woff = 0;
    for (int w = 0; w < wid; ++w) woff += wsum[w];
    if (t < nb) bsum[t] = woff + v - s;  // exclusive block offset
}

__global__ __launch_bounds__(256) void k_fill(const int* __restrict__ deg,
                                              const int* __restrict__ boff,
                                              int* __restrict__ rowptr,
                                              int* __restrict__ cursor,
                                              int N, int Etot) {
    int t = threadIdx.x;
    int base = blockIdx.x * 1024 + t * 4;
    int d[4];
#pragma unroll
    for (int j = 0; j < 4; ++j) d[j] = (base + j < N) ? (deg[base + j] + 1) : 0;
    int s = d[0] + d[1] + d[2] + d[3];
    int lane = t & 63, wid = t >> 6;
    int v = s;
#pragma unroll
    for (int off = 1; off < 64; off <<= 1) {
        int u = __shfl_up(v, off, 64);
        if (lane >= off) v += u;
    }
    __shared__ int wsum[4];
    if (lane == 63) wsum[wid] = v;
    __syncthreads();
    int woff = 0;
    for (int w = 0; w < wid; ++w) woff += wsum[w];
    int off0 = boff[blockIdx.x] + woff + v - s;
#pragma unroll
    for (int j = 0; j < 4; ++j) {
        int idx = base + j;
        if (idx < N) { rowptr[idx] = off0; cursor[idx] = off0; }
        off0 += d[j];
    }
    if (blockIdx.x == 0 && t == 0) rowptr[N] = Etot;
}

__global__ void k_scatter(const int* __restrict__ edge_index, int* __restrict__ cursor,
                          int* __restrict__ csr, int E, int N) {
    int i = blockIdx.x * blockDim.x + threadIdx.x;
    if (i >= E + N) return;
    int s, d;
    if (i < E) { s = edge_index[i]; d = edge_index[E + i]; }
    else       { s = i - E; d = s; }
    int pos = atomicAdd(cursor + d, 1);
    csr[pos] = s;
}

// transpose both layers' convW [256 x 64] -> wt [64 x 256] in one dispatch
__global__ void k_wt2(const float* __restrict__ convW0, const float* __restrict__ convW1,
                      float* __restrict__ wt0, float* __restrict__ wt1) {
    int i = blockIdx.x * blockDim.x + threadIdx.x;
    int j = i & 16383;
    int co = j >> 6, k = j & 63;
    if (i < 16384) wt0[k * 256 + co] = convW0[j];
    else           wt1[k * 256 + co] = convW1[j];
}

// xh[n][256] = h[n] @ convW.T (stored bf16); as/ad[n][h] fused via shuffle reduce.
#define TN 16
__global__ __launch_bounds__(256) void k_xh(
        const float* __restrict__ h, const float* __restrict__ wt,
        const float* __restrict__ att_src, const float* __restrict__ att_dst,
        __hip_bfloat16* __restrict__ xh, float* __restrict__ as_, float* __restrict__ ad_,
        int N) {
    __shared__ float hs[TN][64];
    int t = threadIdx.x;
    int n0 = blockIdx.x * TN;
    for (int i = t; i < TN * 64; i += 256) {
        int n = n0 + (i >> 6);
        hs[i >> 6][i & 63] = (n < N) ? h[(size_t)n * 64 + (i & 63)] : 0.f;
    }
    __syncthreads();
    float acc[TN];
#pragma unroll
    for (int j = 0; j < TN; ++j) acc[j] = 0.f;
    const float* wp = wt + t;
#pragma unroll 4
    for (int k4 = 0; k4 < 16; ++k4) {
        float w0 = wp[(k4 * 4 + 0) * 256];
        float w1 = wp[(k4 * 4 + 1) * 256];
        float w2 = wp[(k4 * 4 + 2) * 256];
        float w3 = wp[(k4 * 4 + 3) * 256];
#pragma unroll
        for (int j = 0; j < TN; ++j) {
            float4 hv = *(const float4*)&hs[j][k4 * 4];  // broadcast ds_read_b128
            acc[j] = fmaf(hv.x, w0, fmaf(hv.y, w1, fmaf(hv.z, w2, fmaf(hv.w, w3, acc[j]))));
        }
    }
    float asv = att_src[t], adv = att_dst[t];
    int head = t >> 6, lane = t & 63;
#pragma unroll
    for (int j = 0; j < TN; ++j) {
        int n = n0 + j;
        if (n < N) xh[(size_t)n * 256 + t] = __float2bfloat16(acc[j]);
        float vs = acc[j] * asv;
        float vd = acc[j] * adv;
#pragma unroll
        for (int off = 32; off >= 1; off >>= 1) {
            vs += __shfl_xor(vs, off, 64);
            vd += __shfl_xor(vd, off, 64);
        }
        if (lane == 0 && n < N) {
            as_[n * 4 + head] = vs;
            ad_[n * 4 + head] = vd;
        }
    }
}

// One wave per dst node; each iteration covers TWO edges:
// lanes 0-31 -> edge i, lanes 32-63 -> edge i+1. Lane owns 8 channels
// (row element l32*8, one uint4 of bf16), head = l32>>3.
// Software-pipelined: next pair's csr/as_/xh loads issue during current compute.
__global__ __launch_bounds__(256) void k_gat(
        const __hip_bfloat16* __restrict__ xh, const float* __restrict__ as_,
        const float* __restrict__ ad_, const int* __restrict__ rowptr,
        const int* __restrict__ csr, const float* __restrict__ convb,
        const float* __restrict__ ln_g, const float* __restrict__ ln_b,
        float* __restrict__ h, int N) {
    int wid = threadIdx.x >> 6, lane = threadIdx.x & 63;
    int n = blockIdx.x * 4 + wid;
    if (n >= N) return;
    int half = lane >> 5;     // which edge of the pair
    int l32  = lane & 31;
    int head = l32 >> 3;
    int r0 = rowptr[n], r1 = rowptr[n + 1];
    float adv = ad_[(size_t)n * 4 + head];

    float s = 0.f;
    float a0 = 0.f, a1 = 0.f, a2 = 0.f, a3 = 0.f;
    float a4 = 0.f, a5 = 0.f, a6 = 0.f, a7 = 0.f;

    // prologue loads for the first pair
    int idx = r0 + half;
    bool v = idx < r1;
    int src = csr[v ? idx : (r1 - 1)];
    float asv = as_[(size_t)src * 4 + head];
    uint4 p = *(const uint4*)(xh + (size_t)src * 256 + l32 * 8);

    for (int i = r0; i < r1; i += 2) {
        // current pair's values
        bool vc = v; float asc = asv; uint4 pc = p;
        // issue next pair's loads
        int idxN = i + 2 + half;
        v = idxN < r1;
        if (v) {
            src = csr[idxN];
            asv = as_[(size_t)src * 4 + head];
            p = *(const uint4*)(xh + (size_t)src * 256 + l32 * 8);
        }
        // compute current pair
        float e = asc + adv;
        e = e > 0.f ? e : NEG_SLOPE * e;
        float w = __expf(e);
        w = vc ? w : 0.f;
        s += w;
        a0 = fmaf(w, __uint_as_float(pc.x << 16),          a0);
        a1 = fmaf(w, __uint_as_float(pc.x & 0xffff0000u),  a1);
        a2 = fmaf(w, __uint_as_float(pc.y << 16),          a2);
        a3 = fmaf(w, __uint_as_float(pc.y & 0xffff0000u),  a3);
        a4 = fmaf(w, __uint_as_float(pc.z << 16),          a4);
        a5 = fmaf(w, __uint_as_float(pc.z & 0xffff0000u),  a5);
        a6 = fmaf(w, __uint_as_float(pc.w << 16),          a6);
        a7 = fmaf(w, __uint_as_float(pc.w & 0xffff0000u),  a7);
    }

    // fold the two halves (edge subsets)
    s  += __shfl_xor(s, 32, 64);
    a0 += __shfl_xor(a0, 32, 64); a1 += __shfl_xor(a1, 32, 64);
    a2 += __shfl_xor(a2, 32, 64); a3 += __shfl_xor(a3, 32, 64);
    a4 += __shfl_xor(a4, 32, 64); a5 += __shfl_xor(a5, 32, 64);
    a6 += __shfl_xor(a6, 32, 64); a7 += __shfl_xor(a7, 32, 64);
    float inv = 1.f / (s + 1e-16f);
    a0 *= inv; a1 *= inv; a2 *= inv; a3 *= inv;
    a4 *= inv; a5 *= inv; a6 *= inv; a7 *= inv;
    // sum over the 4 heads (bits 3,4 of l32)
#pragma unroll
    for (int off = 8; off <= 16; off <<= 1) {
        a0 += __shfl_xor(a0, off, 64); a1 += __shfl_xor(a1, off, 64);
        a2 += __shfl_xor(a2, off, 64); a3 += __shfl_xor(a3, off, 64);
        a4 += __shfl_xor(a4, off, 64); a5 += __shfl_xor(a5, off, 64);
        a6 += __shfl_xor(a6, off, 64); a7 += __shfl_xor(a7, off, 64);
    }
    int cbase = (l32 & 7) * 8;  // output channel block
    float4 cbA = *(const float4*)(convb + cbase);
    float4 cbB = *(const float4*)(convb + cbase + 4);
    float o0 = 0.25f * a0 + cbA.x, o1 = 0.25f * a1 + cbA.y;
    float o2 = 0.25f * a2 + cbA.z, o3 = 0.25f * a3 + cbA.w;
    float o4 = 0.25f * a4 + cbB.x, o5 = 0.25f * a5 + cbB.y;
    float o6 = 0.25f * a6 + cbB.z, o7 = 0.25f * a7 + cbB.w;
    // LayerNorm over 64 channels (8/lane across 8-lane channel groups)
    float part = o0 + o1 + o2 + o3 + o4 + o5 + o6 + o7;
#pragma unroll
    for (int off = 1; off <= 4; off <<= 1) part += __shfl_xor(part, off, 64);
    float mu = part * (1.f / 64.f);
    float d0 = o0 - mu, d1 = o1 - mu, d2 = o2 - mu, d3 = o3 - mu;
    float d4 = o4 - mu, d5 = o5 - mu, d6 = o6 - mu, d7 = o7 - mu;
    float vs = d0*d0 + d1*d1 + d2*d2 + d3*d3 + d4*d4 + d5*d5 + d6*d6 + d7*d7;
#pragma unroll
    for (int off = 1; off <= 4; off <<= 1) vs += __shfl_xor(vs, off, 64);
    float rstd = rsqrtf(vs * (1.f / 64.f) + LN_EPS);
    float4 gA = *(const float4*)(ln_g + cbase);
    float4 gB = *(const float4*)(ln_g + cbase + 4);
    float4 bA = *(const float4*)(ln_b + cbase);
    float4 bB = *(const float4*)(ln_b + cbase + 4);
    if (lane < 8) {
        float4* hp = (float4*)(h + (size_t)n * 64 + cbase);
        float4 hA = hp[0], hB = hp[1];
        hA.x += fmaxf(d0 * rstd * gA.x + bA.x, 0.f);
        hA.y += fmaxf(d1 * rstd * gA.y + bA.y, 0.f);
        hA.z += fmaxf(d2 * rstd * gA.z + bA.z, 0.f);
        hA.w += fmaxf(d3 * rstd * gA.w + bA.w, 0.f);
        hB.x += fmaxf(d4 * rstd * gB.x + bB.x, 0.f);
        hB.y += fmaxf(d5 * rstd * gB.y + bB.y, 0.f);
        hB.z += fmaxf(d6 * rstd * gB.z + bB.z, 0.f);
        hB.w += fmaxf(d7 * rstd * gB.w + bB.w, 0.f);
        hp[0] = hA; hp[1] = hB;
    }
}

__global__ void k_out(const float* __restrict__ h, const float* __restrict__ out_W,
                      const float* __restrict__ out_b, float* __restrict__ out, int N) {
    __shared__ float hs[8][64];
    int t = threadIdx.x;
    int n0 = blockIdx.x * 8;
    for (int i = t; i < 512; i += 256) {
        int n = n0 + (i >> 6);
        hs[i >> 6][i & 63] = (n < N) ? h[n * 64 + (i & 63)] : 0.f;
    }
    __syncthreads();
    int j = t >> 5, o = t & 31;
    int n = n0 + j;
    if (n >= N) return;
    float acc = out_b[o];
    const float* w = out_W + o * 64;
#pragma unroll
    for (int k = 0; k < 64; ++k) acc += hs[j][k] * w[k];
    out[n * 32 + o] = acc;
}

static inline unsigned cdiv(long long a, long long b) { return (unsigned)((a + b - 1) / b); }

extern "C" void kernel_launch(void* const* d_in, const int* in_sizes, int n_in,
                              void* d_out, int out_size, void* d_ws, size_t ws_size,
                              hipStream_t stream) {
    const float* x          = (const float*)d_in[0];
    const float* drone_feat = (const float*)d_in[1];
    const int*   edge_index = (const int*)d_in[2];
    const int*   batch      = (const int*)d_in[3];
    const float* node_W     = (const float*)d_in[4];
    const float* node_b     = (const float*)d_in[5];
    const float* drone_W    = (const float*)d_in[6];
    const float* drone_b    = (const float*)d_in[7];
    const float* convW[2]   = {(const float*)d_in[8],  (const float*)d_in[14]};
    const float* att_src[2] = {(const float*)d_in[9],  (const float*)d_in[15]};
    const float* att_dst[2] = {(const float*)d_in[10], (const float*)d_in[16]};
    const float* convb[2]   = {(const float*)d_in[11], (const float*)d_in[17]};
    const float* ln_g[2]    = {(const float*)d_in[12], (const float*)d_in[18]};
    const float* ln_b[2]    = {(const float*)d_in[13], (const float*)d_in[19]};
    const float* out_W      = (const float*)d_in[20];
    const float* out_b      = (const float*)d_in[21];
    float* out = (float*)d_out;

    const int N = in_sizes[0] / 32;
    const int G = in_sizes[1] / 16;
    const int E = in_sizes[2] / 2;
    const int Etot = E + N;
    const int NB = cdiv(N, 1024);  // blocks for hierarchical scan (<=256)

    char* base = (char*)d_ws;
    size_t off = 0;
    auto alloc = [&](size_t bytes) {
        char* p = base + off;
        off = (off + bytes + 255) & ~(size_t)255;
        return p;
    };
    float*           h      = (float*)alloc((size_t)N * 64 * 4);
    __hip_bfloat16*  xh     = (__hip_bfloat16*)alloc((size_t)N * 256 * 2);
    float*           as_    = (float*)alloc((size_t)N * 4 * 4);
    float*           ad_    = (float*)alloc((size_t)N * 4 * 4);
    float*           dr     = (float*)alloc((size_t)G * 64 * 4);
    float*           wt0    = (float*)alloc((size_t)256 * 64 * 4);
    float*           wt1    = (float*)alloc((size_t)256 * 64 * 4);
    int*             deg    = (int*)alloc((size_t)N * 4);
    int*             rowptr = (int*)alloc((size_t)(N + 1) * 4);
    int*             cursor = (int*)alloc((size_t)N * 4);
    int*             csr    = (int*)alloc((size_t)Etot * 4);
    int*             bsum   = (int*)alloc((size_t)256 * 4);
    (void)ws_size;
    const float* wt[2] = {wt0, wt1};

    k_dr<<<cdiv((long long)G * 64, 256), 256, 0, stream>>>(drone_feat, drone_W, drone_b, dr, G);
    k_h0<<<cdiv((long long)N * 64, 256), 256, 0, stream>>>(x, batch, node_W, node_b, dr, h, N);

    hipMemsetAsync(deg, 0, (size_t)N * 4, stream);
    k_count<<<cdiv(E, 256), 256, 0, stream>>>(edge_index, deg, E);
    k_bsum<<<NB, 256, 0, stream>>>(deg, bsum, N);
    k_bscan<<<1, 256, 0, stream>>>(bsum, NB);
    k_fill<<<NB, 256, 0, stream>>>(deg, bsum, rowptr, cursor, N, Etot);
    k_scatter<<<cdiv(Etot, 256), 256, 0, stream>>>(edge_index, cursor, csr, E, N);

    k_wt2<<<cdiv(2 * 16384, 256), 256, 0, stream>>>(convW[0], convW[1], wt0, wt1);

    for (int l = 0; l < 2; ++l) {
        k_xh<<<cdiv(N, TN), 256, 0, stream>>>(h, wt[l], att_src[l], att_dst[l],
                                              xh, as_, ad_, N);
        k_gat<<<cdiv(N, 4), 256, 0, stream>>>(xh, as_, ad_, rowptr, csr, convb[l],
                                              ln_g[l], ln_b[l], h, N);
    }

    k_out<<<cdiv(N, 8), 256, 0, stream>>>(h, out_W, out_b, out, N);
}

// Round 6
// 994.577 us; speedup vs baseline: 5.6191x; 1.0028x over previous
//
#include <hip/hip_runtime.h>
#include <hip/hip_bf16.h>
#include <math.h>

// N=100000, E=1600000, G=64, H=4, C=64, NODE_F=32, DRONE_F=16, OUT=32, L=2

#define NEG_SLOPE 0.2f
#define LN_EPS 1e-5f

// ---------------------------------------------------------------------------
__global__ void k_dr(const float* __restrict__ drone_feat,
                     const float* __restrict__ drone_W,
                     const float* __restrict__ drone_b,
                     float* __restrict__ dr, int G) {
    int i = blockIdx.x * blockDim.x + threadIdx.x;  // g*64 + c
    if (i >= G * 64) return;
    int g = i >> 6, c = i & 63;
    float acc = drone_b[c];
    const float* df = drone_feat + g * 16;
    const float* w  = drone_W + c * 16;
#pragma unroll
    for (int j = 0; j < 16; ++j) acc += df[j] * w[j];
    dr[i] = acc;
}

__global__ void k_h0(const float* __restrict__ x,
                     const int* __restrict__ batch,
                     const float* __restrict__ node_W,
                     const float* __restrict__ node_b,
                     const float* __restrict__ dr,
                     float* __restrict__ h, int N) {
    int i = blockIdx.x * blockDim.x + threadIdx.x;  // n*64 + c
    if (i >= N * 64) return;
    int n = i >> 6, c = i & 63;
    float acc = node_b[c] + dr[batch[n] * 64 + c];
    const float* xr = x + n * 32;
    const float* w  = node_W + c * 32;
#pragma unroll
    for (int k = 0; k < 32; ++k) acc += xr[k] * w[k];
    h[i] = acc;
}

__global__ void k_count(const int* __restrict__ edge_index, int* __restrict__ deg, int E) {
    int i = blockIdx.x * blockDim.x + threadIdx.x;
    if (i < E) atomicAdd(deg + edge_index[E + i], 1);
}

// --- hierarchical scan of (deg+1) -> rowptr/cursor (self loop implicit) -----
__global__ __launch_bounds__(256) void k_bsum(const int* __restrict__ deg,
                                              int* __restrict__ bsum, int N) {
    int t = threadIdx.x;
    int base = blockIdx.x * 1024 + t * 4;
    int s = 0;
#pragma unroll
    for (int j = 0; j < 4; ++j) s += (base + j < N) ? (deg[base + j] + 1) : 0;
    int lane = t & 63, wid = t >> 6;
#pragma unroll
    for (int off = 32; off >= 1; off >>= 1) s += __shfl_xor(s, off, 64);
    __shared__ int ws[4];
    if (lane == 0) ws[wid] = s;
    __syncthreads();
    if (t == 0) bsum[blockIdx.x] = ws[0] + ws[1] + ws[2] + ws[3];
}

__global__ __launch_bounds__(256) void k_bscan(int* __restrict__ bsum, int nb) {
    int t = threadIdx.x;
    int s = (t < nb) ? bsum[t] : 0;
    int lane = t & 63, wid = t >> 6;
    int v = s;
#pragma unroll
    for (int off = 1; off < 64; off <<= 1) {
        int u = __shfl_up(v, off, 64);
        if (lane >= off) v += u;
    }
    __shared__ int wsum[4];
    if (lane == 63) wsum[wid] = v;
    __syncthreads();
    int woff = 0;
    for (int w = 0; w < wid; ++w) woff += wsum[w];
    if (t < nb) bsum[t] = woff + v - s;  // exclusive block offset
}

__global__ __launch_bounds__(256) void k_fill(const int* __restrict__ deg,
                                              const int* __restrict__ boff,
                                              int* __restrict__ rowptr,
                                              int* __restrict__ cursor,
                                              int N, int Etot) {
    int t = threadIdx.x;
    int base = blockIdx.x * 1024 + t * 4;
    int d[4];
#pragma unroll
    for (int j = 0; j < 4; ++j) d[j] = (base + j < N) ? (deg[base + j] + 1) : 0;
    int s = d[0] + d[1] + d[2] + d[3];
    int lane = t & 63, wid = t >> 6;
    int v = s;
#pragma unroll
    for (int off = 1; off < 64; off <<= 1) {
        int u = __shfl_up(v, off, 64);
        if (lane >= off) v += u;
    }
    __shared__ int wsum[4];
    if (lane == 63) wsum[wid] = v;
    __syncthreads();
    int woff = 0;
    for (int w = 0; w < wid; ++w) woff += wsum[w];
    int off0 = boff[blockIdx.x] + woff + v - s;
#pragma unroll
    for (int j = 0; j < 4; ++j) {
        int idx = base + j;
        if (idx < N) { rowptr[idx] = off0; cursor[idx] = off0; }
        off0 += d[j];
    }
    if (blockIdx.x == 0 && t == 0) rowptr[N] = Etot;
}

__global__ void k_scatter(const int* __restrict__ edge_index, int* __restrict__ cursor,
                          int* __restrict__ csr, int E, int N) {
    int i = blockIdx.x * blockDim.x + threadIdx.x;
    if (i >= E + N) return;
    int s, d;
    if (i < E) { s = edge_index[i]; d = edge_index[E + i]; }
    else       { s = i - E; d = s; }
    int pos = atomicAdd(cursor + d, 1);
    csr[pos] = s;
}

// transpose both layers' convW [256 x 64] -> wt [64 x 256] in one dispatch
__global__ void k_wt2(const float* __restrict__ convW0, const float* __restrict__ convW1,
                      float* __restrict__ wt0, float* __restrict__ wt1) {
    int i = blockIdx.x * blockDim.x + threadIdx.x;
    int j = i & 16383;
    int co = j >> 6, k = j & 63;
    if (i < 16384) wt0[k * 256 + co] = convW0[j];
    else           wt1[k * 256 + co] = convW1[j];
}

// uv[l][sd][head][k] = sum_c convW_l[head*64+c][k] * att_{src,dst}_l[head][c]
// Lets as_/ad_ be computed from h directly (exact modulo fp reorder):
// as[n][head] = sum_k h[n][k] * uv[l][0][head][k]
__global__ void k_uv(const float* __restrict__ cW0, const float* __restrict__ s0,
                     const float* __restrict__ d0,  const float* __restrict__ cW1,
                     const float* __restrict__ s1,  const float* __restrict__ d1,
                     float* __restrict__ uv) {
    int i = blockIdx.x * blockDim.x + threadIdx.x;  // 1024
    if (i >= 1024) return;
    int l = i >> 9, sd = (i >> 8) & 1, head = (i >> 6) & 3, k = i & 63;
    const float* W   = l ? cW1 : cW0;
    const float* att = l ? (sd ? d1 : s1) : (sd ? d0 : s0);
    float acc = 0.f;
    for (int c = 0; c < 64; ++c)
        acc += W[(head * 64 + c) * 64 + k] * att[head * 64 + c];
    uv[i] = acc;
}

// as_/ad_[n][head] from h and uv (one thread per (n, head, sd))
__global__ __launch_bounds__(256) void k_att(
        const float* __restrict__ h, const float* __restrict__ uv_l,
        float* __restrict__ as_, float* __restrict__ ad_, int N) {
    int i = blockIdx.x * blockDim.x + threadIdx.x;
    if (i >= N * 8) return;
    int n = i >> 3, head = (i >> 1) & 3, sd = i & 1;
    const float4* u  = (const float4*)(uv_l + sd * 256 + head * 64);
    const float4* hr = (const float4*)(h + (size_t)n * 64);
    float acc = 0.f;
#pragma unroll
    for (int k = 0; k < 16; ++k) {
        float4 hv = hr[k], un = u[k];
        acc += hv.x * un.x + hv.y * un.y + hv.z * un.z + hv.w * un.w;
    }
    (sd ? ad_ : as_)[n * 4 + head] = acc;
}

// xh[n][256] = h[n] @ convW.T (stored bf16) — pure GEMM, no epilogue.
#define TN 16
__global__ __launch_bounds__(256) void k_xh(
        const float* __restrict__ h, const float* __restrict__ wt,
        __hip_bfloat16* __restrict__ xh, int N) {
    __shared__ float hs[TN][64];
    int t = threadIdx.x;
    int n0 = blockIdx.x * TN;
    for (int i = t; i < TN * 64; i += 256) {
        int n = n0 + (i >> 6);
        hs[i >> 6][i & 63] = (n < N) ? h[(size_t)n * 64 + (i & 63)] : 0.f;
    }
    __syncthreads();
    float acc[TN];
#pragma unroll
    for (int j = 0; j < TN; ++j) acc[j] = 0.f;
    const float* wp = wt + t;
#pragma unroll 4
    for (int k4 = 0; k4 < 16; ++k4) {
        float w0 = wp[(k4 * 4 + 0) * 256];
        float w1 = wp[(k4 * 4 + 1) * 256];
        float w2 = wp[(k4 * 4 + 2) * 256];
        float w3 = wp[(k4 * 4 + 3) * 256];
#pragma unroll
        for (int j = 0; j < TN; ++j) {
            float4 hv = *(const float4*)&hs[j][k4 * 4];  // broadcast ds_read_b128
            acc[j] = fmaf(hv.x, w0, fmaf(hv.y, w1, fmaf(hv.z, w2, fmaf(hv.w, w3, acc[j]))));
        }
    }
#pragma unroll
    for (int j = 0; j < TN; ++j) {
        int n = n0 + j;
        if (n < N) xh[(size_t)n * 256 + t] = __float2bfloat16(acc[j]);
    }
}

// One wave per dst node; two edges per iteration (lanes 0-31 edge i, 32-63
// edge i+1); lane owns 8 channels (uint4 of bf16). Depth-2 software pipeline:
// csr for i+4 and as_/xh for i+2 issue at iteration i (clamped, branchless).
__global__ __launch_bounds__(256) void k_gat(
        const __hip_bfloat16* __restrict__ xh, const float* __restrict__ as_,
        const float* __restrict__ ad_, const int* __restrict__ rowptr,
        const int* __restrict__ csr, const float* __restrict__ convb,
        const float* __restrict__ ln_g, const float* __restrict__ ln_b,
        float* __restrict__ h, int N) {
    int wid = threadIdx.x >> 6, lane = threadIdx.x & 63;
    int n = blockIdx.x * 4 + wid;
    if (n >= N) return;
    int half = lane >> 5;     // which edge of the pair
    int l32  = lane & 31;
    int head = l32 >> 3;
    int r0 = rowptr[n], r1 = rowptr[n + 1];
    float adv = ad_[(size_t)n * 4 + head];

    float s = 0.f;
    float a0 = 0.f, a1 = 0.f, a2 = 0.f, a3 = 0.f;
    float a4 = 0.f, a5 = 0.f, a6 = 0.f, a7 = 0.f;

    // prologue: stage0 = pair at r0, stage1 = pair at r0+2
    int idx0 = r0 + half;
    int idx1 = r0 + 2 + half;
    bool v0 = idx0 < r1;
    bool v1 = idx1 < r1;
    int clamp = r1 - 1;                      // always valid (deg >= 1)
    int src0 = csr[v0 ? idx0 : clamp];
    int src1 = csr[v1 ? idx1 : clamp];
    float as0 = as_[(size_t)src0 * 4 + head];
    uint4 p0 = *(const uint4*)(xh + (size_t)src0 * 256 + l32 * 8);

    for (int i = r0; i < r1; i += 2) {
        // consume stage0
        bool vc = v0; float asc = as0; uint4 pc = p0;
        // shift: stage1 -> stage0 loads; new csr load for i+4
        int srcc = src1;
        v0 = v1;
        int idx2 = i + 4 + half;
        v1 = idx2 < r1;
        src1 = csr[v1 ? idx2 : clamp];
        as0 = as_[(size_t)srcc * 4 + head];
        p0 = *(const uint4*)(xh + (size_t)srcc * 256 + l32 * 8);
        // compute current pair
        float e = asc + adv;
        e = e > 0.f ? e : NEG_SLOPE * e;
        float w = __expf(e);
        w = vc ? w : 0.f;
        s += w;
        a0 = fmaf(w, __uint_as_float(pc.x << 16),          a0);
        a1 = fmaf(w, __uint_as_float(pc.x & 0xffff0000u),  a1);
        a2 = fmaf(w, __uint_as_float(pc.y << 16),          a2);
        a3 = fmaf(w, __uint_as_float(pc.y & 0xffff0000u),  a3);
        a4 = fmaf(w, __uint_as_float(pc.z << 16),          a4);
        a5 = fmaf(w, __uint_as_float(pc.z & 0xffff0000u),  a5);
        a6 = fmaf(w, __uint_as_float(pc.w << 16),          a6);
        a7 = fmaf(w, __uint_as_float(pc.w & 0xffff0000u),  a7);
    }

    // fold the two halves (edge subsets)
    s  += __shfl_xor(s, 32, 64);
    a0 += __shfl_xor(a0, 32, 64); a1 += __shfl_xor(a1, 32, 64);
    a2 += __shfl_xor(a2, 32, 64); a3 += __shfl_xor(a3, 32, 64);
    a4 += __shfl_xor(a4, 32, 64); a5 += __shfl_xor(a5, 32, 64);
    a6 += __shfl_xor(a6, 32, 64); a7 += __shfl_xor(a7, 32, 64);
    float inv = 1.f / (s + 1e-16f);
    a0 *= inv; a1 *= inv; a2 *= inv; a3 *= inv;
    a4 *= inv; a5 *= inv; a6 *= inv; a7 *= inv;
    // sum over the 4 heads (bits 3,4 of l32)
#pragma unroll
    for (int off = 8; off <= 16; off <<= 1) {
        a0 += __shfl_xor(a0, off, 64); a1 += __shfl_xor(a1, off, 64);
        a2 += __shfl_xor(a2, off, 64); a3 += __shfl_xor(a3, off, 64);
        a4 += __shfl_xor(a4, off, 64); a5 += __shfl_xor(a5, off, 64);
        a6 += __shfl_xor(a6, off, 64); a7 += __shfl_xor(a7, off, 64);
    }
    int cbase = (l32 & 7) * 8;  // output channel block
    float4 cbA = *(const float4*)(convb + cbase);
    float4 cbB = *(const float4*)(convb + cbase + 4);
    float o0 = 0.25f * a0 + cbA.x, o1 = 0.25f * a1 + cbA.y;
    float o2 = 0.25f * a2 + cbA.z, o3 = 0.25f * a3 + cbA.w;
    float o4 = 0.25f * a4 + cbB.x, o5 = 0.25f * a5 + cbB.y;
    float o6 = 0.25f * a6 + cbB.z, o7 = 0.25f * a7 + cbB.w;
    // LayerNorm over 64 channels (8/lane across 8-lane channel groups)
    float part = o0 + o1 + o2 + o3 + o4 + o5 + o6 + o7;
#pragma unroll
    for (int off = 1; off <= 4; off <<= 1) part += __shfl_xor(part, off, 64);
    float mu = part * (1.f / 64.f);
    float d0 = o0 - mu, d1 = o1 - mu, d2 = o2 - mu, d3 = o3 - mu;
    float d4 = o4 - mu, d5 = o5 - mu, d6 = o6 - mu, d7 = o7 - mu;
    float vs = d0*d0 + d1*d1 + d2*d2 + d3*d3 + d4*d4 + d5*d5 + d6*d6 + d7*d7;
#pragma unroll
    for (int off = 1; off <= 4; off <<= 1) vs += __shfl_xor(vs, off, 64);
    float rstd = rsqrtf(vs * (1.f / 64.f) + LN_EPS);
    float4 gA = *(const float4*)(ln_g + cbase);
    float4 gB = *(const float4*)(ln_g + cbase + 4);
    float4 bA = *(const float4*)(ln_b + cbase);
    float4 bB = *(const float4*)(ln_b + cbase + 4);
    if (lane < 8) {
        float4* hp = (float4*)(h + (size_t)n * 64 + cbase);
        float4 hA = hp[0], hB = hp[1];
        hA.x += fmaxf(d0 * rstd * gA.x + bA.x, 0.f);
        hA.y += fmaxf(d1 * rstd * gA.y + bA.y, 0.f);
        hA.z += fmaxf(d2 * rstd * gA.z + bA.z, 0.f);
        hA.w += fmaxf(d3 * rstd * gA.w + bA.w, 0.f);
        hB.x += fmaxf(d4 * rstd * gB.x + bB.x, 0.f);
        hB.y += fmaxf(d5 * rstd * gB.y + bB.y, 0.f);
        hB.z += fmaxf(d6 * rstd * gB.z + bB.z, 0.f);
        hB.w += fmaxf(d7 * rstd * gB.w + bB.w, 0.f);
        hp[0] = hA; hp[1] = hB;
    }
}

__global__ void k_out(const float* __restrict__ h, const float* __restrict__ out_W,
                      const float* __restrict__ out_b, float* __restrict__ out, int N) {
    __shared__ float hs[8][64];
    int t = threadIdx.x;
    int n0 = blockIdx.x * 8;
    for (int i = t; i < 512; i += 256) {
        int n = n0 + (i >> 6);
        hs[i >> 6][i & 63] = (n < N) ? h[n * 64 + (i & 63)] : 0.f;
    }
    __syncthreads();
    int j = t >> 5, o = t & 31;
    int n = n0 + j;
    if (n >= N) return;
    float acc = out_b[o];
    const float* w = out_W + o * 64;
#pragma unroll
    for (int k = 0; k < 64; ++k) acc += hs[j][k] * w[k];
    out[n * 32 + o] = acc;
}

static inline unsigned cdiv(long long a, long long b) { return (unsigned)((a + b - 1) / b); }

extern "C" void kernel_launch(void* const* d_in, const int* in_sizes, int n_in,
                              void* d_out, int out_size, void* d_ws, size_t ws_size,
                              hipStream_t stream) {
    const float* x          = (const float*)d_in[0];
    const float* drone_feat = (const float*)d_in[1];
    const int*   edge_index = (const int*)d_in[2];
    const int*   batch      = (const int*)d_in[3];
    const float* node_W     = (const float*)d_in[4];
    const float* node_b     = (const float*)d_in[5];
    const float* drone_W    = (const float*)d_in[6];
    const float* drone_b    = (const float*)d_in[7];
    const float* convW[2]   = {(const float*)d_in[8],  (const float*)d_in[14]};
    const float* att_src[2] = {(const float*)d_in[9],  (const float*)d_in[15]};
    const float* att_dst[2] = {(const float*)d_in[10], (const float*)d_in[16]};
    const float* convb[2]   = {(const float*)d_in[11], (const float*)d_in[17]};
    const float* ln_g[2]    = {(const float*)d_in[12], (const float*)d_in[18]};
    const float* ln_b[2]    = {(const float*)d_in[13], (const float*)d_in[19]};
    const float* out_W      = (const float*)d_in[20];
    const float* out_b      = (const float*)d_in[21];
    float* out = (float*)d_out;

    const int N = in_sizes[0] / 32;
    const int G = in_sizes[1] / 16;
    const int E = in_sizes[2] / 2;
    const int Etot = E + N;
    const int NB = cdiv(N, 1024);  // blocks for hierarchical scan (<=256)

    char* base = (char*)d_ws;
    size_t off = 0;
    auto alloc = [&](size_t bytes) {
        char* p = base + off;
        off = (off + bytes + 255) & ~(size_t)255;
        return p;
    };
    float*           h      = (float*)alloc((size_t)N * 64 * 4);
    __hip_bfloat16*  xh     = (__hip_bfloat16*)alloc((size_t)N * 256 * 2);
    float*           as_    = (float*)alloc((size_t)N * 4 * 4);
    float*           ad_    = (float*)alloc((size_t)N * 4 * 4);
    float*           dr     = (float*)alloc((size_t)G * 64 * 4);
    float*           wt0    = (float*)alloc((size_t)256 * 64 * 4);
    float*           wt1    = (float*)alloc((size_t)256 * 64 * 4);
    float*           uv     = (float*)alloc((size_t)1024 * 4);
    int*             deg    = (int*)alloc((size_t)N * 4);
    int*             rowptr = (int*)alloc((size_t)(N + 1) * 4);
    int*             cursor = (int*)alloc((size_t)N * 4);
    int*             csr    = (int*)alloc((size_t)Etot * 4);
    int*             bsum   = (int*)alloc((size_t)256 * 4);
    (void)ws_size;
    const float* wt[2] = {wt0, wt1};

    k_dr<<<cdiv((long long)G * 64, 256), 256, 0, stream>>>(drone_feat, drone_W, drone_b, dr, G);
    k_h0<<<cdiv((long long)N * 64, 256), 256, 0, stream>>>(x, batch, node_W, node_b, dr, h, N);

    hipMemsetAsync(deg, 0, (size_t)N * 4, stream);
    k_count<<<cdiv(E, 256), 256, 0, stream>>>(edge_index, deg, E);
    k_bsum<<<NB, 256, 0, stream>>>(deg, bsum, N);
    k_bscan<<<1, 256, 0, stream>>>(bsum, NB);
    k_fill<<<NB, 256, 0, stream>>>(deg, bsum, rowptr, cursor, N, Etot);
    k_scatter<<<cdiv(Etot, 256), 256, 0, stream>>>(edge_index, cursor, csr, E, N);

    k_wt2<<<cdiv(2 * 16384, 256), 256, 0, stream>>>(convW[0], convW[1], wt0, wt1);
    k_uv<<<4, 256, 0, stream>>>(convW[0], att_src[0], att_dst[0],
                                convW[1], att_src[1], att_dst[1], uv);

    for (int l = 0; l < 2; ++l) {
        k_att<<<cdiv((long long)N * 8, 256), 256, 0, stream>>>(h, uv + l * 512, as_, ad_, N);
        k_xh<<<cdiv(N, TN), 256, 0, stream>>>(h, wt[l], xh, N);
        k_gat<<<cdiv(N, 4), 256, 0, stream>>>(xh, as_, ad_, rowptr, csr, convb[l],
                                              ln_g[l], ln_b[l], h, N);
    }

    k_out<<<cdiv(N, 8), 256, 0, stream>>>(h, out_W, out_b, out, N);
}

// Round 8
// 958.825 us; speedup vs baseline: 5.8286x; 1.0373x over previous
//
#include <hip/hip_runtime.h>
#include <hip/hip_bf16.h>
#include <math.h>

// N=100000, E=1600000, G=64, H=4, C=64, NODE_F=32, DRONE_F=16, OUT=32, L=2

#define NEG_SLOPE 0.2f
#define LN_EPS 1e-5f

struct __align__(8) bf16x4 { __hip_bfloat16 x, y, z, w; };

// ---------------------------------------------------------------------------
__global__ void k_dr(const float* __restrict__ drone_feat,
                     const float* __restrict__ drone_W,
                     const float* __restrict__ drone_b,
                     float* __restrict__ dr, int G) {
    int i = blockIdx.x * blockDim.x + threadIdx.x;  // g*64 + c
    if (i >= G * 64) return;
    int g = i >> 6, c = i & 63;
    float acc = drone_b[c];
    const float* df = drone_feat + g * 16;
    const float* w  = drone_W + c * 16;
#pragma unroll
    for (int j = 0; j < 16; ++j) acc += df[j] * w[j];
    dr[i] = acc;
}

__global__ void k_h0(const float* __restrict__ x,
                     const int* __restrict__ batch,
                     const float* __restrict__ node_W,
                     const float* __restrict__ node_b,
                     const float* __restrict__ dr,
                     float* __restrict__ h, int N) {
    int i = blockIdx.x * blockDim.x + threadIdx.x;  // n*64 + c
    if (i >= N * 64) return;
    int n = i >> 6, c = i & 63;
    float acc = node_b[c] + dr[batch[n] * 64 + c];
    const float* xr = x + n * 32;
    const float* w  = node_W + c * 32;
#pragma unroll
    for (int k = 0; k < 32; ++k) acc += xr[k] * w[k];
    h[i] = acc;
}

__global__ void k_count(const int* __restrict__ edge_index, int* __restrict__ deg, int E) {
    int i = blockIdx.x * blockDim.x + threadIdx.x;
    if (i < E) atomicAdd(deg + edge_index[E + i], 1);
}

// --- hierarchical scan of (deg+1) -> rowptr/cursor (self loop implicit) -----
__global__ __launch_bounds__(256) void k_bsum(const int* __restrict__ deg,
                                              int* __restrict__ bsum, int N) {
    int t = threadIdx.x;
    int base = blockIdx.x * 1024 + t * 4;
    int s = 0;
#pragma unroll
    for (int j = 0; j < 4; ++j) s += (base + j < N) ? (deg[base + j] + 1) : 0;
    int lane = t & 63, wid = t >> 6;
#pragma unroll
    for (int off = 32; off >= 1; off >>= 1) s += __shfl_xor(s, off, 64);
    __shared__ int ws[4];
    if (lane == 0) ws[wid] = s;
    __syncthreads();
    if (t == 0) bsum[blockIdx.x] = ws[0] + ws[1] + ws[2] + ws[3];
}

__global__ __launch_bounds__(256) void k_bscan(int* __restrict__ bsum, int nb) {
    int t = threadIdx.x;
    int s = (t < nb) ? bsum[t] : 0;
    int lane = t & 63, wid = t >> 6;
    int v = s;
#pragma unroll
    for (int off = 1; off < 64; off <<= 1) {
        int u = __shfl_up(v, off, 64);
        if (lane >= off) v += u;
    }
    __shared__ int wsum[4];
    if (lane == 63) wsum[wid] = v;
    __syncthreads();
    int woff = 0;
    for (int w = 0; w < wid; ++w) woff += wsum[w];
    if (t < nb) bsum[t] = woff + v - s;  // exclusive block offset
}

__global__ __launch_bounds__(256) void k_fill(const int* __restrict__ deg,
                                              const int* __restrict__ boff,
                                              int* __restrict__ rowptr,
                                              int* __restrict__ cursor,
                                              int N, int Etot) {
    int t = threadIdx.x;
    int base = blockIdx.x * 1024 + t * 4;
    int d[4];
#pragma unroll
    for (int j = 0; j < 4; ++j) d[j] = (base + j < N) ? (deg[base + j] + 1) : 0;
    int s = d[0] + d[1] + d[2] + d[3];
    int lane = t & 63, wid = t >> 6;
    int v = s;
#pragma unroll
    for (int off = 1; off < 64; off <<= 1) {
        int u = __shfl_up(v, off, 64);
        if (lane >= off) v += u;
    }
    __shared__ int wsum[4];
    if (lane == 63) wsum[wid] = v;
    __syncthreads();
    int woff = 0;
    for (int w = 0; w < wid; ++w) woff += wsum[w];
    int off0 = boff[blockIdx.x] + woff + v - s;
#pragma unroll
    for (int j = 0; j < 4; ++j) {
        int idx = base + j;
        if (idx < N) { rowptr[idx] = off0; cursor[idx] = off0; }
        off0 += d[j];
    }
    if (blockIdx.x == 0 && t == 0) rowptr[N] = Etot;
}

__global__ void k_scatter(const int* __restrict__ edge_index, int* __restrict__ cursor,
                          int* __restrict__ csr, int E, int N) {
    int i = blockIdx.x * blockDim.x + threadIdx.x;
    if (i >= E + N) return;
    int s, d;
    if (i < E) { s = edge_index[i]; d = edge_index[E + i]; }
    else       { s = i - E; d = s; }
    int pos = atomicAdd(cursor + d, 1);
    csr[pos] = s;
}

// transpose both layers' convW [256 x 64] -> wt [64 x 256] in one dispatch
__global__ void k_wt2(const float* __restrict__ convW0, const float* __restrict__ convW1,
                      float* __restrict__ wt0, float* __restrict__ wt1) {
    int i = blockIdx.x * blockDim.x + threadIdx.x;
    int j = i & 16383;
    int co = j >> 6, k = j & 63;
    if (i < 16384) wt0[k * 256 + co] = convW0[j];
    else           wt1[k * 256 + co] = convW1[j];
}

// uv[l][sd][head][k] = sum_c convW_l[head*64+c][k] * att_{src,dst}_l[head][c]
__global__ void k_uv(const float* __restrict__ cW0, const float* __restrict__ s0,
                     const float* __restrict__ d0,  const float* __restrict__ cW1,
                     const float* __restrict__ s1,  const float* __restrict__ d1,
                     float* __restrict__ uv) {
    int i = blockIdx.x * blockDim.x + threadIdx.x;  // 1024
    if (i >= 1024) return;
    int l = i >> 9, sd = (i >> 8) & 1, head = (i >> 6) & 3, k = i & 63;
    const float* W   = l ? cW1 : cW0;
    const float* att = l ? (sd ? d1 : s1) : (sd ? d0 : s0);
    float acc = 0.f;
    for (int c = 0; c < 64; ++c)
        acc += W[(head * 64 + c) * 64 + k] * att[head * 64 + c];
    uv[i] = acc;
}

// xh[n][256] = h[n] @ convW.T (bf16) + fused as_/ad_ computation.
// 16 nodes per 256-thread block. Wave w handles nodes w*4..w*4+3; thread t
// computes the float4 of output channels (t&63)*4..+3 for its wave's 4 nodes.
// One broadcast ds_read_b128 feeds 16 FMAs (was 4) -> FMA-bound, not LDS-bound.
#define XPAD 68
__global__ __launch_bounds__(256) void k_xh(
        const float* __restrict__ h, const float* __restrict__ wt,
        const float* __restrict__ uv_l, __hip_bfloat16* __restrict__ xh,
        float* __restrict__ as_, float* __restrict__ ad_, int N) {
    __shared__ float hs[16][XPAD];
    int t = threadIdx.x;
    int n0 = blockIdx.x * 16;
    for (int i = t; i < 16 * 64; i += 256) {
        int r = i >> 6, c = i & 63;
        int n = n0 + r;
        hs[r][c] = (n < N) ? h[(size_t)n * 64 + c] : 0.f;
    }
    __syncthreads();
    int co4 = (t & 63) * 4;   // output channels co4..co4+3
    int nsub = t >> 6;        // wave id -> nodes nsub*4..+3
    float4 acc[4];
#pragma unroll
    for (int j = 0; j < 4; ++j) acc[j] = make_float4(0.f, 0.f, 0.f, 0.f);
    const float* wp = wt + co4;
#pragma unroll 4
    for (int k4 = 0; k4 < 16; ++k4) {
        float4 w0 = *(const float4*)(wp + (k4 * 4 + 0) * 256);
        float4 w1 = *(const float4*)(wp + (k4 * 4 + 1) * 256);
        float4 w2 = *(const float4*)(wp + (k4 * 4 + 2) * 256);
        float4 w3 = *(const float4*)(wp + (k4 * 4 + 3) * 256);
#pragma unroll
        for (int j = 0; j < 4; ++j) {
            float4 hv = *(const float4*)&hs[nsub * 4 + j][k4 * 4];  // broadcast b128
            float4 a = acc[j];
            a.x = fmaf(hv.x, w0.x, fmaf(hv.y, w1.x, fmaf(hv.z, w2.x, fmaf(hv.w, w3.x, a.x))));
            a.y = fmaf(hv.x, w0.y, fmaf(hv.y, w1.y, fmaf(hv.z, w2.y, fmaf(hv.w, w3.y, a.y))));
            a.z = fmaf(hv.x, w0.z, fmaf(hv.y, w1.z, fmaf(hv.z, w2.z, fmaf(hv.w, w3.z, a.z))));
            a.w = fmaf(hv.x, w0.w, fmaf(hv.y, w1.w, fmaf(hv.z, w2.w, fmaf(hv.w, w3.w, a.w))));
            acc[j] = a;
        }
    }
#pragma unroll
    for (int j = 0; j < 4; ++j) {
        int n = n0 + nsub * 4 + j;
        if (n < N) {
            bf16x4 o;
            o.x = __float2bfloat16(acc[j].x);
            o.y = __float2bfloat16(acc[j].y);
            o.z = __float2bfloat16(acc[j].z);
            o.w = __float2bfloat16(acc[j].w);
            *(bf16x4*)(xh + (size_t)n * 256 + co4) = o;
        }
    }
    // fused as_/ad_: 128 threads each compute one (node, head, sd) dot vs uv
    if (t < 128) {
        int row  = t >> 3;          // 0..15
        int head = (t >> 1) & 3;
        int sd   = t & 1;
        int n = n0 + row;
        if (n < N) {
            const float* u = uv_l + sd * 256 + head * 64;
            float a = 0.f;
#pragma unroll
            for (int k4 = 0; k4 < 16; ++k4) {
                float4 hv = *(const float4*)&hs[row][k4 * 4];
                float4 uu = *(const float4*)(u + k4 * 4);
                a += hv.x * uu.x + hv.y * uu.y + hv.z * uu.z + hv.w * uu.w;
            }
            (sd ? ad_ : as_)[n * 4 + head] = a;
        }
    }
}

// One wave per dst node; two edges per iteration (lanes 0-31 edge i, 32-63
// edge i+1); lane owns 8 channels (uint4 of bf16). Depth-1 pipeline (R5 best).
__global__ __launch_bounds__(256) void k_gat(
        const __hip_bfloat16* __restrict__ xh, const float* __restrict__ as_,
        const float* __restrict__ ad_, const int* __restrict__ rowptr,
        const int* __restrict__ csr, const float* __restrict__ convb,
        const float* __restrict__ ln_g, const float* __restrict__ ln_b,
        float* __restrict__ h, int N) {
    int wid = threadIdx.x >> 6, lane = threadIdx.x & 63;
    int n = blockIdx.x * 4 + wid;
    if (n >= N) return;
    int half = lane >> 5;     // which edge of the pair
    int l32  = lane & 31;
    int head = l32 >> 3;
    int r0 = rowptr[n], r1 = rowptr[n + 1];
    float adv = ad_[(size_t)n * 4 + head];

    float s = 0.f;
    float a0 = 0.f, a1 = 0.f, a2 = 0.f, a3 = 0.f;
    float a4 = 0.f, a5 = 0.f, a6 = 0.f, a7 = 0.f;

    int idx = r0 + half;
    bool v = idx < r1;
    int src = csr[v ? idx : (r1 - 1)];
    float asv = as_[(size_t)src * 4 + head];
    uint4 p = *(const uint4*)(xh + (size_t)src * 256 + l32 * 8);

    for (int i = r0; i < r1; i += 2) {
        bool vc = v; float asc = asv; uint4 pc = p;
        int idxN = i + 2 + half;
        v = idxN < r1;
        if (v) {
            src = csr[idxN];
            asv = as_[(size_t)src * 4 + head];
            p = *(const uint4*)(xh + (size_t)src * 256 + l32 * 8);
        }
        float e = asc + adv;
        e = e > 0.f ? e : NEG_SLOPE * e;
        float w = __expf(e);
        w = vc ? w : 0.f;
        s += w;
        a0 = fmaf(w, __uint_as_float(pc.x << 16),          a0);
        a1 = fmaf(w, __uint_as_float(pc.x & 0xffff0000u),  a1);
        a2 = fmaf(w, __uint_as_float(pc.y << 16),          a2);
        a3 = fmaf(w, __uint_as_float(pc.y & 0xffff0000u),  a3);
        a4 = fmaf(w, __uint_as_float(pc.z << 16),          a4);
        a5 = fmaf(w, __uint_as_float(pc.z & 0xffff0000u),  a5);
        a6 = fmaf(w, __uint_as_float(pc.w << 16),          a6);
        a7 = fmaf(w, __uint_as_float(pc.w & 0xffff0000u),  a7);
    }

    s  += __shfl_xor(s, 32, 64);
    a0 += __shfl_xor(a0, 32, 64); a1 += __shfl_xor(a1, 32, 64);
    a2 += __shfl_xor(a2, 32, 64); a3 += __shfl_xor(a3, 32, 64);
    a4 += __shfl_xor(a4, 32, 64); a5 += __shfl_xor(a5, 32, 64);
    a6 += __shfl_xor(a6, 32, 64); a7 += __shfl_xor(a7, 32, 64);
    float inv = 1.f / (s + 1e-16f);
    a0 *= inv; a1 *= inv; a2 *= inv; a3 *= inv;
    a4 *= inv; a5 *= inv; a6 *= inv; a7 *= inv;
#pragma unroll
    for (int off = 8; off <= 16; off <<= 1) {
        a0 += __shfl_xor(a0, off, 64); a1 += __shfl_xor(a1, off, 64);
        a2 += __shfl_xor(a2, off, 64); a3 += __shfl_xor(a3, off, 64);
        a4 += __shfl_xor(a4, off, 64); a5 += __shfl_xor(a5, off, 64);
        a6 += __shfl_xor(a6, off, 64); a7 += __shfl_xor(a7, off, 64);
    }
    int cbase = (l32 & 7) * 8;
    float4 cbA = *(const float4*)(convb + cbase);
    float4 cbB = *(const float4*)(convb + cbase + 4);
    float o0 = 0.25f * a0 + cbA.x, o1 = 0.25f * a1 + cbA.y;
    float o2 = 0.25f * a2 + cbA.z, o3 = 0.25f * a3 + cbA.w;
    float o4 = 0.25f * a4 + cbB.x, o5 = 0.25f * a5 + cbB.y;
    float o6 = 0.25f * a6 + cbB.z, o7 = 0.25f * a7 + cbB.w;
    float part = o0 + o1 + o2 + o3 + o4 + o5 + o6 + o7;
#pragma unroll
    for (int off = 1; off <= 4; off <<= 1) part += __shfl_xor(part, off, 64);
    float mu = part * (1.f / 64.f);
    float d0 = o0 - mu, d1 = o1 - mu, d2 = o2 - mu, d3 = o3 - mu;
    float d4 = o4 - mu, d5 = o5 - mu, d6 = o6 - mu, d7 = o7 - mu;
    float vs = d0*d0 + d1*d1 + d2*d2 + d3*d3 + d4*d4 + d5*d5 + d6*d6 + d7*d7;
#pragma unroll
    for (int off = 1; off <= 4; off <<= 1) vs += __shfl_xor(vs, off, 64);
    float rstd = rsqrtf(vs * (1.f / 64.f) + LN_EPS);
    float4 gA = *(const float4*)(ln_g + cbase);
    float4 gB = *(const float4*)(ln_g + cbase + 4);
    float4 bA = *(const float4*)(ln_b + cbase);
    float4 bB = *(const float4*)(ln_b + cbase + 4);
    if (lane < 8) {
        float4* hp = (float4*)(h + (size_t)n * 64 + cbase);
        float4 hA = hp[0], hB = hp[1];
        hA.x += fmaxf(d0 * rstd * gA.x + bA.x, 0.f);
        hA.y += fmaxf(d1 * rstd * gA.y + bA.y, 0.f);
        hA.z += fmaxf(d2 * rstd * gA.z + bA.z, 0.f);
        hA.w += fmaxf(d3 * rstd * gA.w + bA.w, 0.f);
        hB.x += fmaxf(d4 * rstd * gB.x + bB.x, 0.f);
        hB.y += fmaxf(d5 * rstd * gB.y + bB.y, 0.f);
        hB.z += fmaxf(d6 * rstd * gB.z + bB.z, 0.f);
        hB.w += fmaxf(d7 * rstd * gB.w + bB.w, 0.f);
        hp[0] = hA; hp[1] = hB;
    }
}

__global__ void k_out(const float* __restrict__ h, const float* __restrict__ out_W,
                      const float* __restrict__ out_b, float* __restrict__ out, int N) {
    __shared__ float hs[8][64];
    int t = threadIdx.x;
    int n0 = blockIdx.x * 8;
    for (int i = t; i < 512; i += 256) {
        int n = n0 + (i >> 6);
        hs[i >> 6][i & 63] = (n < N) ? h[n * 64 + (i & 63)] : 0.f;
    }
    __syncthreads();
    int j = t >> 5, o = t & 31;
    int n = n0 + j;
    if (n >= N) return;
    float acc = out_b[o];
    const float* w = out_W + o * 64;
#pragma unroll
    for (int k = 0; k < 64; ++k) acc += hs[j][k] * w[k];
    out[n * 32 + o] = acc;
}

static inline unsigned cdiv(long long a, long long b) { return (unsigned)((a + b - 1) / b); }

extern "C" void kernel_launch(void* const* d_in, const int* in_sizes, int n_in,
                              void* d_out, int out_size, void* d_ws, size_t ws_size,
                              hipStream_t stream) {
    const float* x          = (const float*)d_in[0];
    const float* drone_feat = (const float*)d_in[1];
    const int*   edge_index = (const int*)d_in[2];
    const int*   batch      = (const int*)d_in[3];
    const float* node_W     = (const float*)d_in[4];
    const float* node_b     = (const float*)d_in[5];
    const float* drone_W    = (const float*)d_in[6];
    const float* drone_b    = (const float*)d_in[7];
    const float* convW[2]   = {(const float*)d_in[8],  (const float*)d_in[14]};
    const float* att_src[2] = {(const float*)d_in[9],  (const float*)d_in[15]};
    const float* att_dst[2] = {(const float*)d_in[10], (const float*)d_in[16]};
    const float* convb[2]   = {(const float*)d_in[11], (const float*)d_in[17]};
    const float* ln_g[2]    = {(const float*)d_in[12], (const float*)d_in[18]};
    const float* ln_b[2]    = {(const float*)d_in[13], (const float*)d_in[19]};
    const float* out_W      = (const float*)d_in[20];
    const float* out_b      = (const float*)d_in[21];
    float* out = (float*)d_out;

    const int N = in_sizes[0] / 32;
    const int G = in_sizes[1] / 16;
    const int E = in_sizes[2] / 2;
    const int Etot = E + N;
    const int NB = cdiv(N, 1024);  // blocks for hierarchical scan (<=256)

    char* base = (char*)d_ws;
    size_t off = 0;
    auto alloc = [&](size_t bytes) {
        char* p = base + off;
        off = (off + bytes + 255) & ~(size_t)255;
        return p;
    };
    float*           h      = (float*)alloc((size_t)N * 64 * 4);
    __hip_bfloat16*  xh     = (__hip_bfloat16*)alloc((size_t)N * 256 * 2);
    float*           as_    = (float*)alloc((size_t)N * 4 * 4);
    float*           ad_    = (float*)alloc((size_t)N * 4 * 4);
    float*           dr     = (float*)alloc((size_t)G * 64 * 4);
    float*           wt0    = (float*)alloc((size_t)256 * 64 * 4);
    float*           wt1    = (float*)alloc((size_t)256 * 64 * 4);
    float*           uv     = (float*)alloc((size_t)1024 * 4);
    int*             deg    = (int*)alloc((size_t)N * 4);
    int*             rowptr = (int*)alloc((size_t)(N + 1) * 4);
    int*             cursor = (int*)alloc((size_t)N * 4);
    int*             csr    = (int*)alloc((size_t)Etot * 4);
    int*             bsum   = (int*)alloc((size_t)256 * 4);
    (void)ws_size;
    const float* wt[2] = {wt0, wt1};

    k_dr<<<cdiv((long long)G * 64, 256), 256, 0, stream>>>(drone_feat, drone_W, drone_b, dr, G);
    k_h0<<<cdiv((long long)N * 64, 256), 256, 0, stream>>>(x, batch, node_W, node_b, dr, h, N);

    (void)hipMemsetAsync(deg, 0, (size_t)N * 4, stream);
    k_count<<<cdiv(E, 256), 256, 0, stream>>>(edge_index, deg, E);
    k_bsum<<<NB, 256, 0, stream>>>(deg, bsum, N);
    k_bscan<<<1, 256, 0, stream>>>(bsum, NB);
    k_fill<<<NB, 256, 0, stream>>>(deg, bsum, rowptr, cursor, N, Etot);
    k_scatter<<<cdiv(Etot, 256), 256, 0, stream>>>(edge_index, cursor, csr, E, N);

    k_wt2<<<cdiv(2 * 16384, 256), 256, 0, stream>>>(convW[0], convW[1], wt0, wt1);
    k_uv<<<4, 256, 0, stream>>>(convW[0], att_src[0], att_dst[0],
                                convW[1], att_src[1], att_dst[1], uv);

    for (int l = 0; l < 2; ++l) {
        k_xh<<<cdiv(N, 16), 256, 0, stream>>>(h, wt[l], uv + l * 512, xh, as_, ad_, N);
        k_gat<<<cdiv(N, 4), 256, 0, stream>>>(xh, as_, ad_, rowptr, csr, convb[l],
                                              ln_g[l], ln_b[l], h, N);
    }

    k_out<<<cdiv(N, 8), 256, 0, stream>>>(h, out_W, out_b, out, N);
}